// Round 6
// baseline (6866.673 us; speedup 1.0000x reference)
//
#include <hip/hip_runtime.h>
#include <hip/hip_bf16.h>
#include <cstdint>
#include <cstddef>

// Problem sizes (fixed)
#define BB 64
#define SS 1024
#define II 1024
#define HH 1024
#define G3 3072   // 3*HH

typedef float  f32x4  __attribute__((ext_vector_type(4)));
typedef short  bf16x8 __attribute__((ext_vector_type(8)));

__device__ __forceinline__ unsigned short f2b(float f) {
    unsigned u = __float_as_uint(f);
    u += 0x7FFFu + ((u >> 16) & 1u);   // RNE
    return (unsigned short)(u >> 16);
}
__device__ __forceinline__ float b2f(unsigned short s) {
    return __uint_as_float(((unsigned)s) << 16);
}

// Interleaved h-slab layout (per 16-batch group, j = hidden index 0..1023):
//   elem offset F(b,j) = (j>>3)*128 + b*8 + (j&7)     (16K bf16 = 32KB slab)
// K-slice kg (128 j) = bytes [kg*4KB, (kg+1)*4KB) of the slab, produced by
// exactly blocks jb' = 2kg and 2kg+1 (64 j = 2KB each) -> per-wave pair poll.

// ---------------------------------------------------------------------------
// Kernel 1: gi = x @ W_ih^T + b_ih      (M=B*S=65536, K=1024, N=3072)
// ---------------------------------------------------------------------------
template<int GI_BF16>
__global__ __launch_bounds__(256)
void gi_gemm(const float* __restrict__ X, const float* __restrict__ W,
             const float* __restrict__ bias, void* __restrict__ gi_out)
{
    __shared__ short As[128][40];   // +8 pad breaks bank conflicts
    __shared__ short Bs[128][40];

    const int t    = threadIdx.x;
    const int lane = t & 63;
    const int wave = t >> 6;
    const int m0   = blockIdx.y * 128;
    const int n0   = blockIdx.x * 128;

    f32x4 acc[4][4] = {};

    for (int k0 = 0; k0 < II; k0 += 32) {
        __syncthreads();
        #pragma unroll
        for (int q = 0; q < 4; ++q) {
            int row = (t >> 3) + 32 * q;
            int col = (t & 7) * 4;
            const float4 a = *reinterpret_cast<const float4*>(X + (size_t)(m0 + row) * II + k0 + col);
            const float4 b = *reinterpret_cast<const float4*>(W + (size_t)(n0 + row) * II + k0 + col);
            As[row][col + 0] = (short)f2b(a.x); As[row][col + 1] = (short)f2b(a.y);
            As[row][col + 2] = (short)f2b(a.z); As[row][col + 3] = (short)f2b(a.w);
            Bs[row][col + 0] = (short)f2b(b.x); Bs[row][col + 1] = (short)f2b(b.y);
            Bs[row][col + 2] = (short)f2b(b.z); Bs[row][col + 3] = (short)f2b(b.w);
        }
        __syncthreads();

        const int mb = (wave & 1) * 64;
        const int nb = (wave >> 1) * 64;
        bf16x8 af[4], bf[4];
        #pragma unroll
        for (int i = 0; i < 4; ++i) {
            af[i] = *reinterpret_cast<const bf16x8*>(&As[mb + i * 16 + (lane & 15)][(lane >> 4) * 8]);
            bf[i] = *reinterpret_cast<const bf16x8*>(&Bs[nb + i * 16 + (lane & 15)][(lane >> 4) * 8]);
        }
        #pragma unroll
        for (int mi = 0; mi < 4; ++mi)
            #pragma unroll
            for (int ni = 0; ni < 4; ++ni)
                acc[mi][ni] = __builtin_amdgcn_mfma_f32_16x16x32_bf16(af[mi], bf[ni], acc[mi][ni], 0, 0, 0);
    }

    const int mb = (wave & 1) * 64;
    const int nb = (wave >> 1) * 64;
    #pragma unroll
    for (int ni = 0; ni < 4; ++ni) {
        int ncol = n0 + nb + ni * 16 + (lane & 15);
        float bv = bias[ncol];
        #pragma unroll
        for (int mi = 0; mi < 4; ++mi) {
            int mrow = m0 + mb + mi * 16 + ((lane >> 4) << 2);
            #pragma unroll
            for (int e = 0; e < 4; ++e) {
                float v = acc[mi][ni][e] + bv;
                size_t idx = (size_t)(mrow + e) * G3 + ncol;
                if (GI_BF16) ((unsigned short*)gi_out)[idx] = f2b(v);
                else         ((float*)gi_out)[idx] = v;
            }
        }
    }
}

// ---------------------------------------------------------------------------
// Kernel 2: init  (reset flags, h16[buf0] = bf16(h0) in interleaved layout)
// ---------------------------------------------------------------------------
__global__ __launch_bounds__(256)
void gru_init(const float* __restrict__ h0, unsigned short* __restrict__ h16,
              int* __restrict__ flags)
{
    int i = blockIdx.x * 256 + threadIdx.x;   // i = b*1024 + j, 65536 total
    int b = i >> 10, j = i & 1023;
    int dst = (b >> 4) * 16384 + (j >> 3) * 128 + (b & 15) * 8 + (j & 7);
    h16[dst] = f2b(h0[i]);
    if (i < 2048) flags[i] = 0;   // 64 flags at 16-int (64B) stride
}

// ---------------------------------------------------------------------------
// Kernel 3: sequential scan. Cooperative, 64 blocks x 1024 threads (16 waves).
// group = bid&3 (16 batches), jb = bid>>2 (16 j-blocks of 64 j each).
// Wave w: kg=w&7 (K=128 slice), ng=w>>3 (32-j half -> 6 ntiles of 16 cols).
// Per step: per-wave PAIR poll (only the 2 blocks producing this wave's
// K-slice) -> direct sc1 reg loads of A-frags -> 24 MFMAs -> padded-LDS
// cross-wave K-reduce -> gates -> sc1 publish -> vmcnt(0) drain -> barrier
// -> block flag. Distance-2 WAR on parity buffers is safe because publish
// comes after bar1, and the block's 16 waves collectively poll all 16 blocks.
// NO cache-maintenance ops (acquire/buffer_inv) anywhere in the loop.
// ---------------------------------------------------------------------------
template<int GI_BF16>
__global__ __launch_bounds__(1024, 1)
void gru_scan(const void* __restrict__ gi_v, const float* __restrict__ Whh,
              const float* __restrict__ h0, unsigned short* __restrict__ h16,
              int* __restrict__ flags, float* __restrict__ out)
{
    const int t     = threadIdx.x;
    const int lane  = t & 63;
    const int wave  = t >> 6;          // 0..15
    const int kg    = wave & 7;        // K-slice (128 k)
    const int ng    = wave >> 3;       // j-half (32 j = 6 ntiles)
    const int bid   = blockIdx.x;
    const int group = bid & 3;
    const int jb    = bid >> 2;        // 0..15, 64 j each

    __shared__ float part[16][6][4][68];   // [wave][ntile][e][lane(+pad)] 102KB

    // ---- one-time: preload W_hh slice as MFMA B-fragments (96 VGPR) ----
    // nt = gate*2 + colHi: W row = gate*HH + jb*64 + ng*32 + colHi*16 + (lane&15)
    bf16x8 wf[4][6];
    #pragma unroll
    for (int kc = 0; kc < 4; ++kc) {
        #pragma unroll
        for (int nt = 0; nt < 6; ++nt) {
            int rowg = (nt >> 1) * HH + jb * 64 + ng * 32 + (nt & 1) * 16 + (lane & 15);
            int k    = kg * 128 + kc * 32 + ((lane >> 4) << 3);
            const float4* src = reinterpret_cast<const float4*>(Whh + (size_t)rowg * HH + k);
            float4 f0 = src[0], f1 = src[1];
            bf16x8 w;
            w[0] = (short)f2b(f0.x); w[1] = (short)f2b(f0.y);
            w[2] = (short)f2b(f0.z); w[3] = (short)f2b(f0.w);
            w[4] = (short)f2b(f1.x); w[5] = (short)f2b(f1.y);
            w[6] = (short)f2b(f1.z); w[7] = (short)f2b(f1.w);
            wf[kc][nt] = w;
        }
    }

    const int b_l = t >> 6;            // 0..15 local batch (== wave)
    const int j_l = t & 63;            // 0..63 local j
    const int b_g = (group << 4) + b_l;
    const int j_g = (jb << 6) + j_l;
    float hreg = h0[b_g * HH + j_g];

    // A-frag byte base within slab (add kc*1024 per chunk): wave reads its
    // 4KB K-slice as 4 contiguous 1KB wave-loads
    const int frag_base = (kg * 16 + (lane >> 4)) * 256 + ((lane & 15) << 4);
    // publish byte offset within slab (even-j threads store packed pairs)
    const int prod_off  = ((j_g >> 3) << 8) + (b_l << 4) + ((j_g & 7) << 1);

    // reduce-gather constants
    const int ng_r = j_l >> 5;          // which ng-half produced my columns
    const int c16  = (j_l >> 4) & 1;    // colHi within that half
    const int lp   = ((b_l >> 2) << 4) | (j_l & 15);
    const int e_r  = b_l & 3;

    // per-wave pair poll: the 2 blocks producing K-slice kg (64B-strided flags)
    const int src_fi = (((group << 4) | (kg * 2 + (lane & 1))) << 4);

    for (int s = 0; s < SS; ++s) {
        const int p = s & 1;
        const char* rslab = (const char*)(h16 + (size_t)p * 65536 + group * 16384);
        unsigned short* wslab = h16 + (size_t)(p ^ 1) * 65536 + group * 16384;

        // prefetch gi (independent of h — issues before the poll)
        size_t gib = ((size_t)b_g * SS + s) * G3;
        float ir, iz, inn;
        if (GI_BF16) {
            const unsigned short* g16 = (const unsigned short*)gi_v;
            ir  = b2f(g16[gib + j_g]);
            iz  = b2f(g16[gib + HH + j_g]);
            inn = b2f(g16[gib + 2 * HH + j_g]);
        } else {
            const float* g32 = (const float*)gi_v;
            ir  = g32[gib + j_g];
            iz  = g32[gib + HH + j_g];
            inn = g32[gib + 2 * HH + j_g];
        }

        // fine-grained poll: wait only for THIS wave's 2 producer blocks
        if (s > 0) {
            while (true) {
                int v = __hip_atomic_load(&flags[src_fi], __ATOMIC_RELAXED,
                                          __HIP_MEMORY_SCOPE_AGENT);
                if (__all(v >= s)) break;
            }
            asm volatile("" ::: "memory");
        }

        // ---- A-fragments: direct sc1 loads to registers (slab K-slice) ----
        unsigned long long hv[8];
        #pragma unroll
        for (int kc = 0; kc < 4; ++kc) {
            const unsigned long long* q =
                (const unsigned long long*)(rslab + frag_base + kc * 1024);
            hv[2 * kc]     = __hip_atomic_load(q,     __ATOMIC_RELAXED,
                                               __HIP_MEMORY_SCOPE_AGENT);
            hv[2 * kc + 1] = __hip_atomic_load(q + 1, __ATOMIC_RELAXED,
                                               __HIP_MEMORY_SCOPE_AGENT);
        }

        // ---- gh partials: M=16, N=96 (6 ntiles), K=128 per wave ----
        f32x4 acc[6] = {};
        #pragma unroll
        for (int kc = 0; kc < 4; ++kc) {
            union { unsigned long long q[2]; bf16x8 v; } u;
            u.q[0] = hv[2 * kc]; u.q[1] = hv[2 * kc + 1];
            #pragma unroll
            for (int nt = 0; nt < 6; ++nt)
                acc[nt] = __builtin_amdgcn_mfma_f32_16x16x32_bf16(u.v, wf[kc][nt], acc[nt], 0, 0, 0);
        }

        // scatter-store partials (lane-contiguous scalar stores: 2-way free)
        #pragma unroll
        for (int nt = 0; nt < 6; ++nt)
            #pragma unroll
            for (int e = 0; e < 4; ++e)
                part[wave][nt][e][lane] = acc[nt][e];
        __syncthreads();   // bar1

        // ---- cross-wave K reduce merged with gates (thread owns b_l, j_l) ----
        float hr = 0.f, hz = 0.f, hn = 0.f;
        #pragma unroll
        for (int k2 = 0; k2 < 8; ++k2) {
            hr += part[ng_r * 8 + k2][0 + c16][e_r][lp];
            hz += part[ng_r * 8 + k2][2 + c16][e_r][lp];
            hn += part[ng_r * 8 + k2][4 + c16][e_r][lp];
        }

        // fast gates: sigmoid/tanh via v_exp + v_rcp (saturate correctly)
        float r  = __builtin_amdgcn_rcpf(1.f + __expf(-(ir + hr)));
        float z  = __builtin_amdgcn_rcpf(1.f + __expf(-(iz + hz)));
        float e2 = __expf(2.f * (inn + r * hn));
        float n  = 1.f - 2.f * __builtin_amdgcn_rcpf(e2 + 1.f);
        float hnew = (1.f - z) * n + z * hreg;
        hreg = hnew;

        // ---- publish h (packed bf16 pair, relaxed agent / sc1) ----
        unsigned short myb = f2b(hnew);
        unsigned pv = (unsigned)__shfl_xor((int)(unsigned)myb, 1);
        if (!(j_l & 1)) {
            unsigned val = ((unsigned)myb) | (pv << 16);
            __hip_atomic_store((unsigned*)((char*)wslab + prod_off), val,
                               __ATOMIC_RELAXED, __HIP_MEMORY_SCOPE_AGENT);
        }

        // release: per-wave drain of sc1 stores, barrier, then one flag store
        asm volatile("s_waitcnt vmcnt(0)" ::: "memory");
        __syncthreads();   // bar2 (also separates gather from next part store)
        if (t == 0)
            __hip_atomic_store(&flags[((group << 4) | jb) << 4], s + 1,
                               __ATOMIC_RELAXED, __HIP_MEMORY_SCOPE_AGENT);

        // out store AFTER the release — not part of the recurrence
        out[((size_t)b_g * SS + s) * HH + j_g] = hnew;
    }

    out[(size_t)BB * SS * HH + (size_t)b_g * HH + j_g] = hreg;
}

// ---------------------------------------------------------------------------
// Host launcher
// ---------------------------------------------------------------------------
extern "C" void kernel_launch(void* const* d_in, const int* in_sizes, int n_in,
                              void* d_out, int out_size, void* d_ws, size_t ws_size,
                              hipStream_t stream)
{
    const float* x   = (const float*)d_in[0];
    const float* h0  = (const float*)d_in[1];
    const float* Wih = (const float*)d_in[2];
    const float* Whh = (const float*)d_in[3];
    const float* bih = (const float*)d_in[4];
    float* out = (float*)d_out;

    char* ws = (char*)d_ws;
    unsigned short* h16 = (unsigned short*)ws;               // 2 x 128KiB parity bufs
    int* flags          = (int*)(ws + 262144);               // 64 flags @ 64B stride
    void* gi            = (void*)(ws + (1 << 20));           // 1 MiB offset

    const size_t gi32_bytes = (size_t)BB * SS * G3 * 4;      // 768 MiB
    const size_t gi16_bytes = gi32_bytes / 2;                // 384 MiB
    const bool use_f32 = ws_size >= ((size_t)(1 << 20) + gi32_bytes);
    const bool use_b16 = !use_f32 && ws_size >= ((size_t)(1 << 20) + gi16_bytes);
    if (!use_f32 && !use_b16) return;

    gru_init<<<dim3(256), dim3(256), 0, stream>>>(h0, h16, flags);

    const void* gi_c = gi;
    const float* Whh_c = Whh;
    const float* h0_c = h0;
    unsigned short* h16_c = h16;
    int* flags_c = flags;
    float* out_c = out;
    void* args[] = { (void*)&gi_c, (void*)&Whh_c, (void*)&h0_c,
                     (void*)&h16_c, (void*)&flags_c, (void*)&out_c };

    if (use_f32) {
        gi_gemm<0><<<dim3(24, 512), dim3(256), 0, stream>>>(x, Wih, bih, gi);
        hipLaunchCooperativeKernel((const void*)&gru_scan<0>, dim3(64), dim3(1024),
                                   args, 0, stream);
    } else {
        gi_gemm<1><<<dim3(24, 512), dim3(256), 0, stream>>>(x, Wih, bih, gi);
        hipLaunchCooperativeKernel((const void*)&gru_scan<1>, dim3(64), dim3(1024),
                                   args, 0, stream);
    }
}

// Round 7
// 4750.902 us; speedup vs baseline: 1.4453x; 1.4453x over previous
//
#include <hip/hip_runtime.h>
#include <hip/hip_bf16.h>
#include <cstdint>
#include <cstddef>

// Problem sizes (fixed)
#define BB 64
#define SS 1024
#define II 1024
#define HH 1024
#define G3 3072   // 3*HH

typedef float  f32x4  __attribute__((ext_vector_type(4)));
typedef short  bf16x8 __attribute__((ext_vector_type(8)));
typedef unsigned int u32x4 __attribute__((ext_vector_type(4)));

__device__ __forceinline__ unsigned short f2b(float f) {
    unsigned u = __float_as_uint(f);
    u += 0x7FFFu + ((u >> 16) & 1u);   // RNE
    return (unsigned short)(u >> 16);
}
__device__ __forceinline__ float b2f(unsigned short s) {
    return __uint_as_float(((unsigned)s) << 16);
}

// Tagged h exchange: one u64 word = { hi: tag = step+1, lo: 2 x bf16 }.
// Per group (16 batches) one slab = 8192 words (64KB); two parity slabs.
// Word index W(b,j) = (j>>3)*64 + b*4 + ((j&7)>>1)  (b = batch 0..15 in group).
// Consumers poll the data words themselves with sc1 (coherence-point) loads
// until all tags == s: detection and data arrival are the same round trip.
// No flags, no producer drain on the critical path, no cache maintenance.

// ---------------------------------------------------------------------------
// Kernel 1: gi = x @ W_ih^T + b_ih      (M=B*S=65536, K=1024, N=3072)
// ---------------------------------------------------------------------------
template<int GI_BF16>
__global__ __launch_bounds__(256)
void gi_gemm(const float* __restrict__ X, const float* __restrict__ W,
             const float* __restrict__ bias, void* __restrict__ gi_out)
{
    __shared__ short As[128][40];   // +8 pad breaks bank conflicts
    __shared__ short Bs[128][40];

    const int t    = threadIdx.x;
    const int lane = t & 63;
    const int wave = t >> 6;
    const int m0   = blockIdx.y * 128;
    const int n0   = blockIdx.x * 128;

    f32x4 acc[4][4] = {};

    for (int k0 = 0; k0 < II; k0 += 32) {
        __syncthreads();
        #pragma unroll
        for (int q = 0; q < 4; ++q) {
            int row = (t >> 3) + 32 * q;
            int col = (t & 7) * 4;
            const float4 a = *reinterpret_cast<const float4*>(X + (size_t)(m0 + row) * II + k0 + col);
            const float4 b = *reinterpret_cast<const float4*>(W + (size_t)(n0 + row) * II + k0 + col);
            As[row][col + 0] = (short)f2b(a.x); As[row][col + 1] = (short)f2b(a.y);
            As[row][col + 2] = (short)f2b(a.z); As[row][col + 3] = (short)f2b(a.w);
            Bs[row][col + 0] = (short)f2b(b.x); Bs[row][col + 1] = (short)f2b(b.y);
            Bs[row][col + 2] = (short)f2b(b.z); Bs[row][col + 3] = (short)f2b(b.w);
        }
        __syncthreads();

        const int mb = (wave & 1) * 64;
        const int nb = (wave >> 1) * 64;
        bf16x8 af[4], bf[4];
        #pragma unroll
        for (int i = 0; i < 4; ++i) {
            af[i] = *reinterpret_cast<const bf16x8*>(&As[mb + i * 16 + (lane & 15)][(lane >> 4) * 8]);
            bf[i] = *reinterpret_cast<const bf16x8*>(&Bs[nb + i * 16 + (lane & 15)][(lane >> 4) * 8]);
        }
        #pragma unroll
        for (int mi = 0; mi < 4; ++mi)
            #pragma unroll
            for (int ni = 0; ni < 4; ++ni)
                acc[mi][ni] = __builtin_amdgcn_mfma_f32_16x16x32_bf16(af[mi], bf[ni], acc[mi][ni], 0, 0, 0);
    }

    const int mb = (wave & 1) * 64;
    const int nb = (wave >> 1) * 64;
    #pragma unroll
    for (int ni = 0; ni < 4; ++ni) {
        int ncol = n0 + nb + ni * 16 + (lane & 15);
        float bv = bias[ncol];
        #pragma unroll
        for (int mi = 0; mi < 4; ++mi) {
            int mrow = m0 + mb + mi * 16 + ((lane >> 4) << 2);
            #pragma unroll
            for (int e = 0; e < 4; ++e) {
                float v = acc[mi][ni][e] + bv;
                size_t idx = (size_t)(mrow + e) * G3 + ncol;
                if (GI_BF16) ((unsigned short*)gi_out)[idx] = f2b(v);
                else         ((float*)gi_out)[idx] = v;
            }
        }
    }
}

// ---------------------------------------------------------------------------
// Kernel 2: init — slab0 = {bf16(h0), tag 0}; slab1 tags cleared to 0.
// Must run every launch (graph replay) to erase leftover tags.
// ---------------------------------------------------------------------------
__global__ __launch_bounds__(256)
void gru_init(const float* __restrict__ h0, unsigned long long* __restrict__ hts)
{
    int i = blockIdx.x * 256 + threadIdx.x;    // 32768 pair-threads
    int b  = i >> 9;                           // 0..63
    int j  = (i & 511) << 1;                   // even j
    unsigned val = (unsigned)f2b(h0[b * 1024 + j]) |
                   ((unsigned)f2b(h0[b * 1024 + j + 1]) << 16);
    int g = b >> 4, bl = b & 15;
    int w = (j >> 3) * 64 + bl * 4 + ((j & 7) >> 1);
    hts[(size_t)g * 8192 + w]         = (unsigned long long)val;  // tag 0
    hts[32768 + (size_t)g * 8192 + w] = 0ull;                     // clear slab1
}

// ---------------------------------------------------------------------------
// Kernel 3: sequential scan. Cooperative, 128 blocks x 512 threads (8 waves).
// group = bid&3 (16 batches), jb = bid>>2 (32 j-blocks of 32 j each).
// Wave w owns K-slice [w*128,(w+1)*128) x all 96 cols (3 gates x 32 j).
// Per step: poll-own-data (8x dwordx4 sc1 loads, tag check, retry) -> 24
// MFMAs -> padded-LDS cross-wave K-reduce -> gates -> tagged sc1 publish ->
// out store -> barrier. Publish-after-bar1 + union-of-wave-polls = WAR-safe.
// ---------------------------------------------------------------------------
template<int GI_BF16>
__global__ __launch_bounds__(512, 1)
void gru_scan(const void* __restrict__ gi_v, const float* __restrict__ Whh,
              const float* __restrict__ h0, unsigned long long* __restrict__ hts,
              float* __restrict__ out)
{
    const int t     = threadIdx.x;
    const int lane  = t & 63;
    const int wave  = t >> 6;          // 0..7 = K-group (128 k each)
    const int bid   = blockIdx.x;
    const int group = bid & 3;
    const int jb    = bid >> 2;        // 0..31

    __shared__ float part[8][6][4][68];   // [wave][ntile][e][lane(+pad)] 52KB

    // ---- one-time: preload W_hh slice as MFMA B-fragments (96 VGPR) ----
    bf16x8 wf[4][6];
    #pragma unroll
    for (int kc = 0; kc < 4; ++kc) {
        #pragma unroll
        for (int nt = 0; nt < 6; ++nt) {
            int rowg = (nt >> 1) * HH + jb * 32 + (nt & 1) * 16 + (lane & 15);
            int k    = wave * 128 + kc * 32 + ((lane >> 4) << 3);
            const float4* src = reinterpret_cast<const float4*>(Whh + (size_t)rowg * HH + k);
            float4 f0 = src[0], f1 = src[1];
            bf16x8 w;
            w[0] = (short)f2b(f0.x); w[1] = (short)f2b(f0.y);
            w[2] = (short)f2b(f0.z); w[3] = (short)f2b(f0.w);
            w[4] = (short)f2b(f1.x); w[5] = (short)f2b(f1.y);
            w[6] = (short)f2b(f1.z); w[7] = (short)f2b(f1.w);
            wf[kc][nt] = w;
        }
    }

    const int b_l = t >> 5;            // 0..15 local batch
    const int j_l = t & 31;            // 0..31 local j
    const int b_g = (group << 4) + b_l;
    const int j_g = (jb << 5) + j_l;
    float hreg = h0[b_g * HH + j_g];

    // untagged byte base of this lane's A-frags (tagged = 2x)
    const int frag_base = (wave * 16 + (lane >> 4)) * 256 + ((lane & 15) << 4);
    // tagged u64 word index of this thread's publish pair (even j_l only)
    const int prod_w = (j_g >> 3) * 64 + b_l * 4 + ((j_g & 7) >> 1);

    // reduce-gather constants
    const int nt_r = j_l >> 4;
    const int lp   = ((b_l >> 2) << 4) | (j_l & 15);
    const int e_r  = b_l & 3;

    for (int s = 0; s < SS; ++s) {
        const unsigned su = (unsigned)s;
        const unsigned long long* rslab = hts + (size_t)(s & 1) * 32768 + group * 8192;
        unsigned long long*       wslab = hts + (size_t)((s + 1) & 1) * 32768 + group * 8192;

        // prefetch gi (independent of h — issues before the poll)
        size_t gib = ((size_t)b_g * SS + s) * G3;
        float ir, iz, inn;
        if (GI_BF16) {
            const unsigned short* g16 = (const unsigned short*)gi_v;
            ir  = b2f(g16[gib + j_g]);
            iz  = b2f(g16[gib + HH + j_g]);
            inn = b2f(g16[gib + 2 * HH + j_g]);
        } else {
            const float* g32 = (const float*)gi_v;
            ir  = g32[gib + j_g];
            iz  = g32[gib + HH + j_g];
            inn = g32[gib + 2 * HH + j_g];
        }

        // ---- poll-own-data: 8x dwordx4 sc1 loads of the tagged K-slice,
        //      retry until all 16 embedded tags == s ----
        unsigned long long aA = (unsigned long long)(uintptr_t)
                                ((const char*)rslab + 2 * frag_base);
        unsigned long long aB = aA + 4096;
        u32x4 r0, r1, r2, r3, r4, r5, r6, r7;
        while (true) {
            asm volatile(
                "global_load_dwordx4 %0, %8, off sc1\n\t"
                "global_load_dwordx4 %1, %8, off offset:16 sc1\n\t"
                "global_load_dwordx4 %2, %8, off offset:2048 sc1\n\t"
                "global_load_dwordx4 %3, %8, off offset:2064 sc1\n\t"
                "global_load_dwordx4 %4, %9, off sc1\n\t"
                "global_load_dwordx4 %5, %9, off offset:16 sc1\n\t"
                "global_load_dwordx4 %6, %9, off offset:2048 sc1\n\t"
                "global_load_dwordx4 %7, %9, off offset:2064 sc1\n\t"
                "s_waitcnt vmcnt(0)"
                : "=&v"(r0), "=&v"(r1), "=&v"(r2), "=&v"(r3),
                  "=&v"(r4), "=&v"(r5), "=&v"(r6), "=&v"(r7)
                : "v"(aA), "v"(aB)
                : "memory");
            bool ok = (r0.y == su) & (r0.w == su) & (r1.y == su) & (r1.w == su) &
                      (r2.y == su) & (r2.w == su) & (r3.y == su) & (r3.w == su) &
                      (r4.y == su) & (r4.w == su) & (r5.y == su) & (r5.w == su) &
                      (r6.y == su) & (r6.w == su) & (r7.y == su) & (r7.w == su);
            if (__all(ok)) break;
            __builtin_amdgcn_s_sleep(1);
        }

        // ---- gh partials: M=16, N=96 (6 ntiles), K=128 per wave ----
        f32x4 acc[6] = {};
        {
            union { unsigned d[4]; bf16x8 v; } u;
            u.d[0] = r0.x; u.d[1] = r0.z; u.d[2] = r1.x; u.d[3] = r1.z;
            #pragma unroll
            for (int nt = 0; nt < 6; ++nt)
                acc[nt] = __builtin_amdgcn_mfma_f32_16x16x32_bf16(u.v, wf[0][nt], acc[nt], 0, 0, 0);
            u.d[0] = r2.x; u.d[1] = r2.z; u.d[2] = r3.x; u.d[3] = r3.z;
            #pragma unroll
            for (int nt = 0; nt < 6; ++nt)
                acc[nt] = __builtin_amdgcn_mfma_f32_16x16x32_bf16(u.v, wf[1][nt], acc[nt], 0, 0, 0);
            u.d[0] = r4.x; u.d[1] = r4.z; u.d[2] = r5.x; u.d[3] = r5.z;
            #pragma unroll
            for (int nt = 0; nt < 6; ++nt)
                acc[nt] = __builtin_amdgcn_mfma_f32_16x16x32_bf16(u.v, wf[2][nt], acc[nt], 0, 0, 0);
            u.d[0] = r6.x; u.d[1] = r6.z; u.d[2] = r7.x; u.d[3] = r7.z;
            #pragma unroll
            for (int nt = 0; nt < 6; ++nt)
                acc[nt] = __builtin_amdgcn_mfma_f32_16x16x32_bf16(u.v, wf[3][nt], acc[nt], 0, 0, 0);
        }

        // scatter-store partials (lane-contiguous scalar stores: conflict-free)
        #pragma unroll
        for (int nt = 0; nt < 6; ++nt)
            #pragma unroll
            for (int e = 0; e < 4; ++e)
                part[wave][nt][e][lane] = acc[nt][e];
        __syncthreads();   // bar1 — block-wide join (all waves' polls passed)

        // ---- cross-wave K reduce merged with gates ----
        float hr = 0.f, hz = 0.f, hn = 0.f;
        #pragma unroll
        for (int w = 0; w < 8; ++w) {
            hr += part[w][0 + nt_r][e_r][lp];
            hz += part[w][2 + nt_r][e_r][lp];
            hn += part[w][4 + nt_r][e_r][lp];
        }

        // fast gates: sigmoid/tanh via v_exp + v_rcp (saturate correctly)
        float r  = __builtin_amdgcn_rcpf(1.f + __expf(-(ir + hr)));
        float z  = __builtin_amdgcn_rcpf(1.f + __expf(-(iz + hz)));
        float e2 = __expf(2.f * (inn + r * hn));
        float n  = 1.f - 2.f * __builtin_amdgcn_rcpf(e2 + 1.f);
        float hnew = (1.f - z) * n + z * hreg;
        hreg = hnew;

        // ---- publish h: single u64 {tag s+1, 2 x bf16}, relaxed agent/sc1.
        //      After bar1, so union-of-polls covers the group (WAR-safe). ----
        unsigned short myb = f2b(hnew);
        unsigned pv = (unsigned)__shfl_xor((int)(unsigned)myb, 1);
        if (!(j_l & 1)) {
            unsigned long long word = ((unsigned long long)(su + 1) << 32) |
                                      (unsigned long long)(((unsigned)myb) | (pv << 16));
            __hip_atomic_store(wslab + prod_w, word,
                               __ATOMIC_RELAXED, __HIP_MEMORY_SCOPE_AGENT);
        }

        // out store (not part of the recurrence; drains at next barrier)
        out[((size_t)b_g * SS + s) * HH + j_g] = hnew;

        __syncthreads();   // bar2 — LDS part[] WAR (gather before next store)
    }

    out[(size_t)BB * SS * HH + (size_t)b_g * HH + j_g] = hreg;
}

// ---------------------------------------------------------------------------
// Host launcher
// ---------------------------------------------------------------------------
extern "C" void kernel_launch(void* const* d_in, const int* in_sizes, int n_in,
                              void* d_out, int out_size, void* d_ws, size_t ws_size,
                              hipStream_t stream)
{
    const float* x   = (const float*)d_in[0];
    const float* h0  = (const float*)d_in[1];
    const float* Wih = (const float*)d_in[2];
    const float* Whh = (const float*)d_in[3];
    const float* bih = (const float*)d_in[4];
    float* out = (float*)d_out;

    char* ws = (char*)d_ws;
    unsigned long long* hts = (unsigned long long*)ws;       // 2 x 256KiB tagged slabs
    void* gi = (void*)(ws + (1 << 20));                      // 1 MiB offset

    const size_t gi32_bytes = (size_t)BB * SS * G3 * 4;      // 768 MiB
    const size_t gi16_bytes = gi32_bytes / 2;                // 384 MiB
    const bool use_f32 = ws_size >= ((size_t)(1 << 20) + gi32_bytes);
    const bool use_b16 = !use_f32 && ws_size >= ((size_t)(1 << 20) + gi16_bytes);
    if (!use_f32 && !use_b16) return;

    gru_init<<<dim3(128), dim3(256), 0, stream>>>(h0, hts);

    const void* gi_c = gi;
    const float* Whh_c = Whh;
    const float* h0_c = h0;
    unsigned long long* hts_c = hts;
    float* out_c = out;
    void* args[] = { (void*)&gi_c, (void*)&Whh_c, (void*)&h0_c,
                     (void*)&hts_c, (void*)&out_c };

    if (use_f32) {
        gi_gemm<0><<<dim3(24, 512), dim3(256), 0, stream>>>(x, Wih, bih, gi);
        hipLaunchCooperativeKernel((const void*)&gru_scan<0>, dim3(128), dim3(512),
                                   args, 0, stream);
    } else {
        gi_gemm<1><<<dim3(24, 512), dim3(256), 0, stream>>>(x, Wih, bih, gi);
        hipLaunchCooperativeKernel((const void*)&gru_scan<1>, dim3(128), dim3(512),
                                   args, 0, stream);
    }
}

// Round 11
// 3996.690 us; speedup vs baseline: 1.7181x; 1.1887x over previous
//
#include <hip/hip_runtime.h>
#include <hip/hip_bf16.h>
#include <cstdint>
#include <cstddef>

// Problem sizes (fixed)
#define BB 64
#define SS 1024
#define II 1024
#define HH 1024
#define G3 3072   // 3*HH

typedef float  f32x4  __attribute__((ext_vector_type(4)));
typedef short  bf16x8 __attribute__((ext_vector_type(8)));

__device__ __forceinline__ unsigned short f2b(float f) {
    unsigned u = __float_as_uint(f);
    u += 0x7FFFu + ((u >> 16) & 1u);   // RNE
    return (unsigned short)(u >> 16);
}
__device__ __forceinline__ float b2f(unsigned short s) {
    return __uint_as_float(((unsigned)s) << 16);
}

// Interleaved h-slab layout (per 16-batch group, j = hidden index 0..1023):
//   elem offset F(b,j) = (j>>3)*128 + b*8 + (j&7)     (16K bf16 = 32KB slab)
// Wave w (K-slice [w*128,(w+1)*128)) chunk kc: lane reads 16B at byte
//   (w*16 + kc*4 + (l>>4))*256 + (l&15)*16  -> 1KB contiguous per (w,kc);
// the 8 waves' ranges tile the slab exactly once. Producers of wave w's
// K-slice are blocks jb' = 4w..4w+3 -> per-wave fine poll of 4 flag lines.

// ---------------------------------------------------------------------------
// Kernel 1: gi = x @ W_ih^T + b_ih      (M=B*S=65536, K=1024, N=3072)
// Staging repacked: 2x float4 loads -> short8 -> ONE ds_write_b128 per tile
// per q (was 32 scalar ds_write_b16) — staging was the GEMM bottleneck.
// ---------------------------------------------------------------------------
template<int GI_BF16>
__global__ __launch_bounds__(256)
void gi_gemm(const float* __restrict__ X, const float* __restrict__ W,
             const float* __restrict__ bias, void* __restrict__ gi_out)
{
    __shared__ short As[128][40];   // +8 pad breaks bank conflicts
    __shared__ short Bs[128][40];

    const int t    = threadIdx.x;
    const int lane = t & 63;
    const int wave = t >> 6;
    const int m0   = blockIdx.y * 128;
    const int n0   = blockIdx.x * 128;

    f32x4 acc[4][4] = {};

    for (int k0 = 0; k0 < II; k0 += 32) {
        __syncthreads();
        // stage 128x32 of A (x) and B (W_ih): fp32 -> bf16, packed b128 writes
        #pragma unroll
        for (int q = 0; q < 2; ++q) {
            int row = (t >> 2) + 64 * q;
            int col = (t & 3) * 8;
            const float4* ap = reinterpret_cast<const float4*>(X + (size_t)(m0 + row) * II + k0 + col);
            const float4* bp = reinterpret_cast<const float4*>(W + (size_t)(n0 + row) * II + k0 + col);
            float4 a0 = ap[0], a1 = ap[1];
            float4 b0 = bp[0], b1 = bp[1];
            bf16x8 av, bv;
            av[0] = (short)f2b(a0.x); av[1] = (short)f2b(a0.y);
            av[2] = (short)f2b(a0.z); av[3] = (short)f2b(a0.w);
            av[4] = (short)f2b(a1.x); av[5] = (short)f2b(a1.y);
            av[6] = (short)f2b(a1.z); av[7] = (short)f2b(a1.w);
            bv[0] = (short)f2b(b0.x); bv[1] = (short)f2b(b0.y);
            bv[2] = (short)f2b(b0.z); bv[3] = (short)f2b(b0.w);
            bv[4] = (short)f2b(b1.x); bv[5] = (short)f2b(b1.y);
            bv[6] = (short)f2b(b1.z); bv[7] = (short)f2b(b1.w);
            *reinterpret_cast<bf16x8*>(&As[row][col]) = av;
            *reinterpret_cast<bf16x8*>(&Bs[row][col]) = bv;
        }
        __syncthreads();

        const int mb = (wave & 1) * 64;
        const int nb = (wave >> 1) * 64;
        bf16x8 af[4], bf[4];
        #pragma unroll
        for (int i = 0; i < 4; ++i) {
            af[i] = *reinterpret_cast<const bf16x8*>(&As[mb + i * 16 + (lane & 15)][(lane >> 4) * 8]);
            bf[i] = *reinterpret_cast<const bf16x8*>(&Bs[nb + i * 16 + (lane & 15)][(lane >> 4) * 8]);
        }
        #pragma unroll
        for (int mi = 0; mi < 4; ++mi)
            #pragma unroll
            for (int ni = 0; ni < 4; ++ni)
                acc[mi][ni] = __builtin_amdgcn_mfma_f32_16x16x32_bf16(af[mi], bf[ni], acc[mi][ni], 0, 0, 0);
    }

    const int mb = (wave & 1) * 64;
    const int nb = (wave >> 1) * 64;
    #pragma unroll
    for (int ni = 0; ni < 4; ++ni) {
        int ncol = n0 + nb + ni * 16 + (lane & 15);
        float bv = bias[ncol];
        #pragma unroll
        for (int mi = 0; mi < 4; ++mi) {
            int mrow = m0 + mb + mi * 16 + ((lane >> 4) << 2);
            #pragma unroll
            for (int e = 0; e < 4; ++e) {
                float v = acc[mi][ni][e] + bv;
                size_t idx = (size_t)(mrow + e) * G3 + ncol;
                if (GI_BF16) ((unsigned short*)gi_out)[idx] = f2b(v);
                else         ((float*)gi_out)[idx] = v;
            }
        }
    }
}

// ---------------------------------------------------------------------------
// Kernel 2: init  (reset flags, h16[buf0] = bf16(h0) in interleaved layout)
// ---------------------------------------------------------------------------
__global__ __launch_bounds__(256)
void gru_init(const float* __restrict__ h0, unsigned short* __restrict__ h16,
              int* __restrict__ flags)
{
    int i = blockIdx.x * 256 + threadIdx.x;   // i = b*1024 + j, 65536 total
    int b = i >> 10, j = i & 1023;
    int dst = (b >> 4) * 16384 + (j >> 3) * 128 + (b & 15) * 8 + (j & 7);
    h16[dst] = f2b(h0[i]);
    if (i < 2048) flags[i] = 0;   // 128 flags at 16-int (64B) stride
}

// ---------------------------------------------------------------------------
// Kernel 3: sequential scan. Cooperative, 128 blocks x 512 threads (8 waves).
// group = bid&3 (16 batches), jb = bid>>2 (32 j-blocks of 32 j each).
// Wave w owns K-slice [w*128,(w+1)*128) x all 96 cols (3 gates x 32 j).
// Per step: per-wave FINE poll (only the 4 producer blocks jb'=4w..4w+3 of
// this wave's K-slice; 4 flag lines/wave instead of 32 — 8x less coherence-
// point poll traffic than round 5) -> direct sc1 reg loads of A-frags ->
// 24 MFMAs -> padded-LDS cross-wave K-reduce -> gates -> sc1 publish ->
// vmcnt(0) drain -> barrier -> block flag. WAR safety: publish is after
// bar1, and the union of the 8 waves' polls covers all 32 blocks at >= s.
// NO cache-maintenance ops (acquire/buffer_inv) anywhere in the loop.
// ---------------------------------------------------------------------------
template<int GI_BF16>
__global__ __launch_bounds__(512, 1)
void gru_scan(const void* __restrict__ gi_v, const float* __restrict__ Whh,
              const float* __restrict__ h0, unsigned short* __restrict__ h16,
              int* __restrict__ flags, float* __restrict__ out)
{
    const int t     = threadIdx.x;
    const int lane  = t & 63;
    const int wave  = t >> 6;          // 0..7 = K-group (128 k each)
    const int bid   = blockIdx.x;
    const int group = bid & 3;
    const int jb    = bid >> 2;        // 0..31

    __shared__ float part[8][6][4][68];   // [wave][ntile][e][lane(+pad)] 52KB

    // ---- one-time: preload W_hh slice as MFMA B-fragments (96 VGPR) ----
    bf16x8 wf[4][6];
    #pragma unroll
    for (int kc = 0; kc < 4; ++kc) {
        #pragma unroll
        for (int nt = 0; nt < 6; ++nt) {
            int rowg = (nt >> 1) * HH + jb * 32 + (nt & 1) * 16 + (lane & 15);
            int k    = wave * 128 + kc * 32 + ((lane >> 4) << 3);
            const float4* src = reinterpret_cast<const float4*>(Whh + (size_t)rowg * HH + k);
            float4 f0 = src[0], f1 = src[1];
            bf16x8 w;
            w[0] = (short)f2b(f0.x); w[1] = (short)f2b(f0.y);
            w[2] = (short)f2b(f0.z); w[3] = (short)f2b(f0.w);
            w[4] = (short)f2b(f1.x); w[5] = (short)f2b(f1.y);
            w[6] = (short)f2b(f1.z); w[7] = (short)f2b(f1.w);
            wf[kc][nt] = w;
        }
    }

    const int b_l = t >> 5;            // 0..15 local batch
    const int j_l = t & 31;            // 0..31 local j
    const int b_g = (group << 4) + b_l;
    const int j_g = (jb << 5) + j_l;
    float hreg = h0[b_g * HH + j_g];

    // A-frag byte base within slab (add kc*1024 per chunk): wave-contiguous 1KB
    const int frag_base = (wave * 16 + (lane >> 4)) * 256 + ((lane & 15) << 4);
    // publish byte offset within slab (even-j threads store packed pairs)
    const int prod_off  = ((j_g >> 3) << 8) + (b_l << 4) + ((j_g & 7) << 1);

    // reduce-gather constants
    const int nt_r = j_l >> 4;
    const int lp   = ((b_l >> 2) << 4) | (j_l & 15);
    const int e_r  = b_l & 3;

    // per-wave fine poll: the 4 blocks producing K-slice [128w,128w+128)
    const int poll_fi = ((group << 5) | (wave << 2) | (lane & 3)) << 4;

    for (int s = 0; s < SS; ++s) {
        const int p = s & 1;
        const char* rslab = (const char*)(h16 + (size_t)p * 65536 + group * 16384);
        unsigned short* wslab = h16 + (size_t)(p ^ 1) * 65536 + group * 16384;

        // prefetch gi (independent of h — issues before the poll)
        size_t gib = ((size_t)b_g * SS + s) * G3;
        float ir, iz, inn;
        if (GI_BF16) {
            const unsigned short* g16 = (const unsigned short*)gi_v;
            ir  = b2f(g16[gib + j_g]);
            iz  = b2f(g16[gib + HH + j_g]);
            inn = b2f(g16[gib + 2 * HH + j_g]);
        } else {
            const float* g32 = (const float*)gi_v;
            ir  = g32[gib + j_g];
            iz  = g32[gib + HH + j_g];
            inn = g32[gib + 2 * HH + j_g];
        }

        // fine-grained poll: wait only for THIS wave's 4 producer blocks
        // (16 lanes share each address -> 4 requests/wave/iteration)
        if (s > 0) {
            while (true) {
                int v = __hip_atomic_load(&flags[poll_fi], __ATOMIC_RELAXED,
                                          __HIP_MEMORY_SCOPE_AGENT);
                if (__all(v >= s)) break;
            }
            asm volatile("" ::: "memory");
        }

        // ---- A-fragments: direct sc1 loads to registers (2x u64 per chunk,
        //      1KB wave-contiguous per (wave,kc); slab read exactly once) ----
        unsigned long long hv[8];
        #pragma unroll
        for (int kc = 0; kc < 4; ++kc) {
            const unsigned long long* q =
                (const unsigned long long*)(rslab + frag_base + kc * 1024);
            hv[2 * kc]     = __hip_atomic_load(q,     __ATOMIC_RELAXED,
                                               __HIP_MEMORY_SCOPE_AGENT);
            hv[2 * kc + 1] = __hip_atomic_load(q + 1, __ATOMIC_RELAXED,
                                               __HIP_MEMORY_SCOPE_AGENT);
        }

        // ---- gh partials: M=16, N=96 (6 ntiles), K=128 per wave ----
        f32x4 acc[6] = {};
        #pragma unroll
        for (int kc = 0; kc < 4; ++kc) {
            union { unsigned long long q[2]; bf16x8 v; } u;
            u.q[0] = hv[2 * kc]; u.q[1] = hv[2 * kc + 1];
            #pragma unroll
            for (int nt = 0; nt < 6; ++nt)
                acc[nt] = __builtin_amdgcn_mfma_f32_16x16x32_bf16(u.v, wf[kc][nt], acc[nt], 0, 0, 0);
        }

        // scatter-store partials (lane-contiguous scalar stores: conflict-free)
        #pragma unroll
        for (int nt = 0; nt < 6; ++nt)
            #pragma unroll
            for (int e = 0; e < 4; ++e)
                part[wave][nt][e][lane] = acc[nt][e];
        __syncthreads();   // bar1 — joins all waves (their polls all passed)

        // ---- cross-wave K reduce merged with gates ----
        float hr = 0.f, hz = 0.f, hn = 0.f;
        #pragma unroll
        for (int w = 0; w < 8; ++w) {
            hr += part[w][0 + nt_r][e_r][lp];
            hz += part[w][2 + nt_r][e_r][lp];
            hn += part[w][4 + nt_r][e_r][lp];
        }

        // fast gates: sigmoid/tanh via v_exp + v_rcp (saturate correctly)
        float r  = __builtin_amdgcn_rcpf(1.f + __expf(-(ir + hr)));
        float z  = __builtin_amdgcn_rcpf(1.f + __expf(-(iz + hz)));
        float e2 = __expf(2.f * (inn + r * hn));
        float n  = 1.f - 2.f * __builtin_amdgcn_rcpf(e2 + 1.f);
        float hnew = (1.f - z) * n + z * hreg;
        hreg = hnew;

        // ---- publish h (packed bf16 pair, relaxed agent / sc1) ----
        unsigned short myb = f2b(hnew);
        unsigned pv = (unsigned)__shfl_xor((int)(unsigned)myb, 1);
        if (!(j_l & 1)) {
            unsigned val = ((unsigned)myb) | (pv << 16);
            __hip_atomic_store((unsigned*)((char*)wslab + prod_off), val,
                               __ATOMIC_RELAXED, __HIP_MEMORY_SCOPE_AGENT);
        }

        // release: drain sc1 stores to coherence point, barrier, flag store
        asm volatile("s_waitcnt vmcnt(0)" ::: "memory");
        __syncthreads();   // bar2 (also separates gather from next part store)
        if (t == 0)
            __hip_atomic_store(&flags[((group << 5) | jb) << 4], s + 1,
                               __ATOMIC_RELAXED, __HIP_MEMORY_SCOPE_AGENT);

        // out store AFTER the release — not part of the recurrence
        out[((size_t)b_g * SS + s) * HH + j_g] = hnew;
    }

    out[(size_t)BB * SS * HH + (size_t)b_g * HH + j_g] = hreg;
}

// ---------------------------------------------------------------------------
// Host launcher
// ---------------------------------------------------------------------------
extern "C" void kernel_launch(void* const* d_in, const int* in_sizes, int n_in,
                              void* d_out, int out_size, void* d_ws, size_t ws_size,
                              hipStream_t stream)
{
    const float* x   = (const float*)d_in[0];
    const float* h0  = (const float*)d_in[1];
    const float* Wih = (const float*)d_in[2];
    const float* Whh = (const float*)d_in[3];
    const float* bih = (const float*)d_in[4];
    float* out = (float*)d_out;

    char* ws = (char*)d_ws;
    unsigned short* h16 = (unsigned short*)ws;               // 2 x 128KiB parity bufs
    int* flags          = (int*)(ws + 262144);               // 128 flags @ 64B stride
    void* gi            = (void*)(ws + (1 << 20));           // 1 MiB offset

    const size_t gi32_bytes = (size_t)BB * SS * G3 * 4;      // 768 MiB
    const size_t gi16_bytes = gi32_bytes / 2;                // 384 MiB
    const bool use_f32 = ws_size >= ((size_t)(1 << 20) + gi32_bytes);
    const bool use_b16 = !use_f32 && ws_size >= ((size_t)(1 << 20) + gi16_bytes);
    if (!use_f32 && !use_b16) return;

    gru_init<<<dim3(256), dim3(256), 0, stream>>>(h0, h16, flags);

    const void* gi_c = gi;
    const float* Whh_c = Whh;
    const float* h0_c = h0;
    unsigned short* h16_c = h16;
    int* flags_c = flags;
    float* out_c = out;
    void* args[] = { (void*)&gi_c, (void*)&Whh_c, (void*)&h0_c,
                     (void*)&h16_c, (void*)&flags_c, (void*)&out_c };

    if (use_f32) {
        gi_gemm<0><<<dim3(24, 512), dim3(256), 0, stream>>>(x, Wih, bih, gi);
        hipLaunchCooperativeKernel((const void*)&gru_scan<0>, dim3(128), dim3(512),
                                   args, 0, stream);
    } else {
        gi_gemm<1><<<dim3(24, 512), dim3(256), 0, stream>>>(x, Wih, bih, gi);
        hipLaunchCooperativeKernel((const void*)&gru_scan<1>, dim3(128), dim3(512),
                                   args, 0, stream);
    }
}

// Round 12
// 3816.450 us; speedup vs baseline: 1.7992x; 1.0472x over previous
//
#include <hip/hip_runtime.h>
#include <hip/hip_bf16.h>
#include <cstdint>
#include <cstddef>

// Problem sizes (fixed)
#define BB 64
#define SS 1024
#define II 1024
#define HH 1024
#define G3 3072   // 3*HH

typedef float  f32x4  __attribute__((ext_vector_type(4)));
typedef short  bf16x8 __attribute__((ext_vector_type(8)));

__device__ __forceinline__ unsigned short f2b(float f) {
    unsigned u = __float_as_uint(f);
    u += 0x7FFFu + ((u >> 16) & 1u);   // RNE
    return (unsigned short)(u >> 16);
}
__device__ __forceinline__ float b2f(unsigned short s) {
    return __uint_as_float(((unsigned)s) << 16);
}

// ---------------------------------------------------------------------------
// Kernel 0: bf16 prepass — xb = bf16(x), wb = bf16(W_ih). One pass, HBM-bound.
// Same RNE as the old inline conversion -> bit-identical GEMM results.
// ---------------------------------------------------------------------------
__global__ __launch_bounds__(256)
void conv_b16(const float* __restrict__ x, const float* __restrict__ w,
              unsigned short* __restrict__ xb, unsigned short* __restrict__ wb)
{
    const size_t XN = (size_t)BB * SS * II;     // 67108864
    const size_t WN = (size_t)G3 * II;          // 3145728
    size_t i = ((size_t)blockIdx.x * 256 + threadIdx.x) * 4;
    if (i < XN) {
        float4 v = *reinterpret_cast<const float4*>(x + i);
        uint2 p;
        p.x = (unsigned)f2b(v.x) | ((unsigned)f2b(v.y) << 16);
        p.y = (unsigned)f2b(v.z) | ((unsigned)f2b(v.w) << 16);
        *reinterpret_cast<uint2*>(xb + i) = p;
    } else {
        size_t j = i - XN;
        if (j < WN) {
            float4 v = *reinterpret_cast<const float4*>(w + j);
            uint2 p;
            p.x = (unsigned)f2b(v.x) | ((unsigned)f2b(v.y) << 16);
            p.y = (unsigned)f2b(v.z) | ((unsigned)f2b(v.w) << 16);
            *reinterpret_cast<uint2*>(wb + j) = p;
        }
    }
}

// ---------------------------------------------------------------------------
// Kernel 1a: gi = xb @ wb^T + b_ih  (bf16 inputs, m97 structure)
// 128x128 tile, BK=64, global_load_lds width-16 into linear [128][64] LDS,
// ds_read_b128 fragments, 32 MFMA/wave/K-tile, fp32 epilogue.
// Flat grid 12288, XCD-swizzled: xcd = bid&7 owns n-panels xcd*3..xcd*3+2
// (W slice 768KB bf16 -> L2-resident), m sweeps with n fastest.
// ---------------------------------------------------------------------------
__global__ __launch_bounds__(256)
void gi_gemm_lds(const unsigned short* __restrict__ XB,
                 const unsigned short* __restrict__ WB,
                 const float* __restrict__ bias, float* __restrict__ gi_out)
{
    __shared__ short As[8192];   // [128][64] bf16, linear (16KB)
    __shared__ short Bs[8192];

    const int t    = threadIdx.x;
    const int lane = t & 63;
    const int wave = t >> 6;
    const int bid  = blockIdx.x;
    const int xcd  = bid & 7;
    const int kseq = bid >> 3;                 // 0..1535
    const int n0   = (xcd * 3 + (kseq % 3)) * 128;
    const int m0   = (kseq / 3) * 128;

    f32x4 acc[4][4] = {};
    const int mb = (wave & 1) * 64;
    const int nb = (wave >> 1) * 64;
    const int lr = lane >> 3;                  // 0..7 row within 8-row stripe
    const int lc = (lane & 7) * 8;             // bf16 col within 64-col window

    for (int k0 = 0; k0 < II; k0 += 64) {
        __syncthreads();   // WAR: previous K-tile's reads done before overwrite
        #pragma unroll
        for (int i2 = 0; i2 < 4; ++i2) {
            const int i = wave * 4 + i2;       // wave-uniform load index 0..15
            const unsigned short* ga = XB + (size_t)(m0 + i * 8 + lr) * II + k0 + lc;
            const unsigned short* gb = WB + (size_t)(n0 + i * 8 + lr) * II + k0 + lc;
            __builtin_amdgcn_global_load_lds(
                (const __attribute__((address_space(1))) void*)ga,
                (__attribute__((address_space(3))) void*)(As + i * 512), 16, 0, 0);
            __builtin_amdgcn_global_load_lds(
                (const __attribute__((address_space(1))) void*)gb,
                (__attribute__((address_space(3))) void*)(Bs + i * 512), 16, 0, 0);
        }
        __syncthreads();   // drains vmcnt(0) then barrier: tiles ready
        #pragma unroll
        for (int ks = 0; ks < 2; ++ks) {
            bf16x8 af[4], bf[4];
            #pragma unroll
            for (int i = 0; i < 4; ++i) {
                af[i] = *reinterpret_cast<const bf16x8*>(
                    As + (mb + i * 16 + (lane & 15)) * 64 + ks * 32 + (lane >> 4) * 8);
                bf[i] = *reinterpret_cast<const bf16x8*>(
                    Bs + (nb + i * 16 + (lane & 15)) * 64 + ks * 32 + (lane >> 4) * 8);
            }
            #pragma unroll
            for (int mi = 0; mi < 4; ++mi)
                #pragma unroll
                for (int ni = 0; ni < 4; ++ni)
                    acc[mi][ni] = __builtin_amdgcn_mfma_f32_16x16x32_bf16(
                        af[mi], bf[ni], acc[mi][ni], 0, 0, 0);
        }
    }

    #pragma unroll
    for (int ni = 0; ni < 4; ++ni) {
        int ncol = n0 + nb + ni * 16 + (lane & 15);
        float bv = bias[ncol];
        #pragma unroll
        for (int mi = 0; mi < 4; ++mi) {
            int mrow = m0 + mb + mi * 16 + ((lane >> 4) << 2);
            #pragma unroll
            for (int e = 0; e < 4; ++e) {
                float v = acc[mi][ni][e] + bv;
                gi_out[(size_t)(mrow + e) * G3 + ncol] = v;
            }
        }
    }
}

// ---------------------------------------------------------------------------
// Kernel 1b (fallback, ws too small for xb/wb): old inline-convert GEMM.
// ---------------------------------------------------------------------------
template<int GI_BF16>
__global__ __launch_bounds__(256)
void gi_gemm(const float* __restrict__ X, const float* __restrict__ W,
             const float* __restrict__ bias, void* __restrict__ gi_out)
{
    __shared__ short As[128][40];
    __shared__ short Bs[128][40];

    const int t    = threadIdx.x;
    const int lane = t & 63;
    const int wave = t >> 6;
    const int m0   = blockIdx.y * 128;
    const int n0   = blockIdx.x * 128;

    f32x4 acc[4][4] = {};

    for (int k0 = 0; k0 < II; k0 += 32) {
        __syncthreads();
        #pragma unroll
        for (int q = 0; q < 2; ++q) {
            int row = (t >> 2) + 64 * q;
            int col = (t & 3) * 8;
            const float4* ap = reinterpret_cast<const float4*>(X + (size_t)(m0 + row) * II + k0 + col);
            const float4* bp = reinterpret_cast<const float4*>(W + (size_t)(n0 + row) * II + k0 + col);
            float4 a0 = ap[0], a1 = ap[1];
            float4 b0 = bp[0], b1 = bp[1];
            bf16x8 av, bv;
            av[0] = (short)f2b(a0.x); av[1] = (short)f2b(a0.y);
            av[2] = (short)f2b(a0.z); av[3] = (short)f2b(a0.w);
            av[4] = (short)f2b(a1.x); av[5] = (short)f2b(a1.y);
            av[6] = (short)f2b(a1.z); av[7] = (short)f2b(a1.w);
            bv[0] = (short)f2b(b0.x); bv[1] = (short)f2b(b0.y);
            bv[2] = (short)f2b(b0.z); bv[3] = (short)f2b(b0.w);
            bv[4] = (short)f2b(b1.x); bv[5] = (short)f2b(b1.y);
            bv[6] = (short)f2b(b1.z); bv[7] = (short)f2b(b1.w);
            *reinterpret_cast<bf16x8*>(&As[row][col]) = av;
            *reinterpret_cast<bf16x8*>(&Bs[row][col]) = bv;
        }
        __syncthreads();

        const int mb = (wave & 1) * 64;
        const int nb = (wave >> 1) * 64;
        bf16x8 af[4], bf[4];
        #pragma unroll
        for (int i = 0; i < 4; ++i) {
            af[i] = *reinterpret_cast<const bf16x8*>(&As[mb + i * 16 + (lane & 15)][(lane >> 4) * 8]);
            bf[i] = *reinterpret_cast<const bf16x8*>(&Bs[nb + i * 16 + (lane & 15)][(lane >> 4) * 8]);
        }
        #pragma unroll
        for (int mi = 0; mi < 4; ++mi)
            #pragma unroll
            for (int ni = 0; ni < 4; ++ni)
                acc[mi][ni] = __builtin_amdgcn_mfma_f32_16x16x32_bf16(af[mi], bf[ni], acc[mi][ni], 0, 0, 0);
    }

    const int mb = (wave & 1) * 64;
    const int nb = (wave >> 1) * 64;
    #pragma unroll
    for (int ni = 0; ni < 4; ++ni) {
        int ncol = n0 + nb + ni * 16 + (lane & 15);
        float bv = bias[ncol];
        #pragma unroll
        for (int mi = 0; mi < 4; ++mi) {
            int mrow = m0 + mb + mi * 16 + ((lane >> 4) << 2);
            #pragma unroll
            for (int e = 0; e < 4; ++e) {
                float v = acc[mi][ni][e] + bv;
                size_t idx = (size_t)(mrow + e) * G3 + ncol;
                if (GI_BF16) ((unsigned short*)gi_out)[idx] = f2b(v);
                else         ((float*)gi_out)[idx] = v;
            }
        }
    }
}

// ---------------------------------------------------------------------------
// Kernel 2: init  (reset flags, h16[buf0] = bf16(h0) in interleaved layout)
// ---------------------------------------------------------------------------
__global__ __launch_bounds__(256)
void gru_init(const float* __restrict__ h0, unsigned short* __restrict__ h16,
              int* __restrict__ flags)
{
    int i = blockIdx.x * 256 + threadIdx.x;   // i = b*1024 + j, 65536 total
    int b = i >> 10, j = i & 1023;
    int dst = (b >> 4) * 16384 + (j >> 3) * 128 + (b & 15) * 8 + (j & 7);
    h16[dst] = f2b(h0[i]);
    if (i < 2048) flags[i] = 0;   // 128 flags at 16-int (64B) stride
}

// ---------------------------------------------------------------------------
// Kernel 3: sequential scan — UNCHANGED from round 11 (proven, 3040 us).
// Cooperative, 128 blocks x 512 threads (8 waves). Per-wave fine poll of the
// 4 producer blocks of this wave's K-slice; sc1 reg loads; 24 MFMAs; padded
// LDS cross-wave reduce; gates; sc1 publish; vmcnt(0); barrier; flag.
// ---------------------------------------------------------------------------
template<int GI_BF16>
__global__ __launch_bounds__(512, 1)
void gru_scan(const void* __restrict__ gi_v, const float* __restrict__ Whh,
              const float* __restrict__ h0, unsigned short* __restrict__ h16,
              int* __restrict__ flags, float* __restrict__ out)
{
    const int t     = threadIdx.x;
    const int lane  = t & 63;
    const int wave  = t >> 6;          // 0..7 = K-group (128 k each)
    const int bid   = blockIdx.x;
    const int group = bid & 3;
    const int jb    = bid >> 2;        // 0..31

    __shared__ float part[8][6][4][68];   // [wave][ntile][e][lane(+pad)] 52KB

    bf16x8 wf[4][6];
    #pragma unroll
    for (int kc = 0; kc < 4; ++kc) {
        #pragma unroll
        for (int nt = 0; nt < 6; ++nt) {
            int rowg = (nt >> 1) * HH + jb * 32 + (nt & 1) * 16 + (lane & 15);
            int k    = wave * 128 + kc * 32 + ((lane >> 4) << 3);
            const float4* src = reinterpret_cast<const float4*>(Whh + (size_t)rowg * HH + k);
            float4 f0 = src[0], f1 = src[1];
            bf16x8 w;
            w[0] = (short)f2b(f0.x); w[1] = (short)f2b(f0.y);
            w[2] = (short)f2b(f0.z); w[3] = (short)f2b(f0.w);
            w[4] = (short)f2b(f1.x); w[5] = (short)f2b(f1.y);
            w[6] = (short)f2b(f1.z); w[7] = (short)f2b(f1.w);
            wf[kc][nt] = w;
        }
    }

    const int b_l = t >> 5;
    const int j_l = t & 31;
    const int b_g = (group << 4) + b_l;
    const int j_g = (jb << 5) + j_l;
    float hreg = h0[b_g * HH + j_g];

    const int frag_base = (wave * 16 + (lane >> 4)) * 256 + ((lane & 15) << 4);
    const int prod_off  = ((j_g >> 3) << 8) + (b_l << 4) + ((j_g & 7) << 1);

    const int nt_r = j_l >> 4;
    const int lp   = ((b_l >> 2) << 4) | (j_l & 15);
    const int e_r  = b_l & 3;

    const int poll_fi = ((group << 5) | (wave << 2) | (lane & 3)) << 4;

    for (int s = 0; s < SS; ++s) {
        const int p = s & 1;
        const char* rslab = (const char*)(h16 + (size_t)p * 65536 + group * 16384);
        unsigned short* wslab = h16 + (size_t)(p ^ 1) * 65536 + group * 16384;

        size_t gib = ((size_t)b_g * SS + s) * G3;
        float ir, iz, inn;
        if (GI_BF16) {
            const unsigned short* g16 = (const unsigned short*)gi_v;
            ir  = b2f(g16[gib + j_g]);
            iz  = b2f(g16[gib + HH + j_g]);
            inn = b2f(g16[gib + 2 * HH + j_g]);
        } else {
            const float* g32 = (const float*)gi_v;
            ir  = g32[gib + j_g];
            iz  = g32[gib + HH + j_g];
            inn = g32[gib + 2 * HH + j_g];
        }

        if (s > 0) {
            while (true) {
                int v = __hip_atomic_load(&flags[poll_fi], __ATOMIC_RELAXED,
                                          __HIP_MEMORY_SCOPE_AGENT);
                if (__all(v >= s)) break;
            }
            asm volatile("" ::: "memory");
        }

        unsigned long long hv[8];
        #pragma unroll
        for (int kc = 0; kc < 4; ++kc) {
            const unsigned long long* q =
                (const unsigned long long*)(rslab + frag_base + kc * 1024);
            hv[2 * kc]     = __hip_atomic_load(q,     __ATOMIC_RELAXED,
                                               __HIP_MEMORY_SCOPE_AGENT);
            hv[2 * kc + 1] = __hip_atomic_load(q + 1, __ATOMIC_RELAXED,
                                               __HIP_MEMORY_SCOPE_AGENT);
        }

        f32x4 acc[6] = {};
        #pragma unroll
        for (int kc = 0; kc < 4; ++kc) {
            union { unsigned long long q[2]; bf16x8 v; } u;
            u.q[0] = hv[2 * kc]; u.q[1] = hv[2 * kc + 1];
            #pragma unroll
            for (int nt = 0; nt < 6; ++nt)
                acc[nt] = __builtin_amdgcn_mfma_f32_16x16x32_bf16(u.v, wf[kc][nt], acc[nt], 0, 0, 0);
        }

        #pragma unroll
        for (int nt = 0; nt < 6; ++nt)
            #pragma unroll
            for (int e = 0; e < 4; ++e)
                part[wave][nt][e][lane] = acc[nt][e];
        __syncthreads();   // bar1

        float hr = 0.f, hz = 0.f, hn = 0.f;
        #pragma unroll
        for (int w = 0; w < 8; ++w) {
            hr += part[w][0 + nt_r][e_r][lp];
            hz += part[w][2 + nt_r][e_r][lp];
            hn += part[w][4 + nt_r][e_r][lp];
        }

        float r  = __builtin_amdgcn_rcpf(1.f + __expf(-(ir + hr)));
        float z  = __builtin_amdgcn_rcpf(1.f + __expf(-(iz + hz)));
        float e2 = __expf(2.f * (inn + r * hn));
        float n  = 1.f - 2.f * __builtin_amdgcn_rcpf(e2 + 1.f);
        float hnew = (1.f - z) * n + z * hreg;
        hreg = hnew;

        unsigned short myb = f2b(hnew);
        unsigned pv = (unsigned)__shfl_xor((int)(unsigned)myb, 1);
        if (!(j_l & 1)) {
            unsigned val = ((unsigned)myb) | (pv << 16);
            __hip_atomic_store((unsigned*)((char*)wslab + prod_off), val,
                               __ATOMIC_RELAXED, __HIP_MEMORY_SCOPE_AGENT);
        }

        asm volatile("s_waitcnt vmcnt(0)" ::: "memory");
        __syncthreads();   // bar2
        if (t == 0)
            __hip_atomic_store(&flags[((group << 5) | jb) << 4], s + 1,
                               __ATOMIC_RELAXED, __HIP_MEMORY_SCOPE_AGENT);

        out[((size_t)b_g * SS + s) * HH + j_g] = hnew;
    }

    out[(size_t)BB * SS * HH + (size_t)b_g * HH + j_g] = hreg;
}

// ---------------------------------------------------------------------------
// Host launcher
// ---------------------------------------------------------------------------
extern "C" void kernel_launch(void* const* d_in, const int* in_sizes, int n_in,
                              void* d_out, int out_size, void* d_ws, size_t ws_size,
                              hipStream_t stream)
{
    const float* x   = (const float*)d_in[0];
    const float* h0  = (const float*)d_in[1];
    const float* Wih = (const float*)d_in[2];
    const float* Whh = (const float*)d_in[3];
    const float* bih = (const float*)d_in[4];
    float* out = (float*)d_out;

    char* ws = (char*)d_ws;
    unsigned short* h16 = (unsigned short*)ws;               // 2 x 128KiB parity bufs
    int* flags          = (int*)(ws + 262144);               // 128 flags @ 64B stride
    void* gi            = (void*)(ws + (1 << 20));           // 1 MiB offset

    const size_t gi32_bytes = (size_t)BB * SS * G3 * 4;      // 768 MiB
    const size_t gi16_bytes = gi32_bytes / 2;                // 384 MiB
    const size_t xb_off  = (size_t)(1 << 20) + gi32_bytes;   // after fp32 gi
    const size_t wb_off  = xb_off + (size_t)BB * SS * II * 2;          // +128 MiB
    const size_t need_new = wb_off + (size_t)G3 * II * 2;              // +6 MiB

    const bool use_new = ws_size >= need_new;
    const bool use_f32 = !use_new && ws_size >= ((size_t)(1 << 20) + gi32_bytes);
    const bool use_b16 = !use_new && !use_f32 &&
                         ws_size >= ((size_t)(1 << 20) + gi16_bytes);
    if (!use_new && !use_f32 && !use_b16) return;

    gru_init<<<dim3(256), dim3(256), 0, stream>>>(h0, h16, flags);

    const void* gi_c = gi;
    const float* Whh_c = Whh;
    const float* h0_c = h0;
    unsigned short* h16_c = h16;
    int* flags_c = flags;
    float* out_c = out;
    void* args[] = { (void*)&gi_c, (void*)&Whh_c, (void*)&h0_c,
                     (void*)&h16_c, (void*)&flags_c, (void*)&out_c };

    if (use_new) {
        unsigned short* xb = (unsigned short*)(ws + xb_off);
        unsigned short* wb = (unsigned short*)(ws + wb_off);
        conv_b16<<<dim3(68608), dim3(256), 0, stream>>>(x, Wih, xb, wb);
        gi_gemm_lds<<<dim3(12288), dim3(256), 0, stream>>>(xb, wb, bih, (float*)gi);
        hipLaunchCooperativeKernel((const void*)&gru_scan<0>, dim3(128), dim3(512),
                                   args, 0, stream);
    } else if (use_f32) {
        gi_gemm<0><<<dim3(24, 512), dim3(256), 0, stream>>>(x, Wih, bih, gi);
        hipLaunchCooperativeKernel((const void*)&gru_scan<0>, dim3(128), dim3(512),
                                   args, 0, stream);
    } else {
        gi_gemm<1><<<dim3(24, 512), dim3(256), 0, stream>>>(x, Wih, bih, gi);
        hipLaunchCooperativeKernel((const void*)&gru_scan<1>, dim3(128), dim3(512),
                                   args, 0, stream);
    }
}

// Round 13
// 3386.245 us; speedup vs baseline: 2.0278x; 1.1270x over previous
//
#include <hip/hip_runtime.h>
#include <hip/hip_bf16.h>
#include <cstdint>
#include <cstddef>

// Problem sizes (fixed)
#define BB 64
#define SS 1024
#define II 1024
#define HH 1024
#define G3 3072   // 3*HH

typedef float  f32x4  __attribute__((ext_vector_type(4)));
typedef short  bf16x8 __attribute__((ext_vector_type(8)));

__device__ __forceinline__ unsigned short f2b(float f) {
    unsigned u = __float_as_uint(f);
    u += 0x7FFFu + ((u >> 16) & 1u);   // RNE
    return (unsigned short)(u >> 16);
}
__device__ __forceinline__ float b2f(unsigned short s) {
    return __uint_as_float(((unsigned)s) << 16);
}

// ---------------------------------------------------------------------------
// Kernel 0: bf16 prepass — xb = bf16(x), wb = bf16(W_ih). One pass, HBM-bound.
// ---------------------------------------------------------------------------
__global__ __launch_bounds__(256)
void conv_b16(const float* __restrict__ x, const float* __restrict__ w,
              unsigned short* __restrict__ xb, unsigned short* __restrict__ wb)
{
    const size_t XN = (size_t)BB * SS * II;     // 67108864
    const size_t WN = (size_t)G3 * II;          // 3145728
    size_t i = ((size_t)blockIdx.x * 256 + threadIdx.x) * 4;
    if (i < XN) {
        float4 v = *reinterpret_cast<const float4*>(x + i);
        uint2 p;
        p.x = (unsigned)f2b(v.x) | ((unsigned)f2b(v.y) << 16);
        p.y = (unsigned)f2b(v.z) | ((unsigned)f2b(v.w) << 16);
        *reinterpret_cast<uint2*>(xb + i) = p;
    } else {
        size_t j = i - XN;
        if (j < WN) {
            float4 v = *reinterpret_cast<const float4*>(w + j);
            uint2 p;
            p.x = (unsigned)f2b(v.x) | ((unsigned)f2b(v.y) << 16);
            p.y = (unsigned)f2b(v.z) | ((unsigned)f2b(v.w) << 16);
            *reinterpret_cast<uint2*>(wb + j) = p;
        }
    }
}

// ---------------------------------------------------------------------------
// Kernel 2: init  (reset flags + chunk counters, h16[buf0] = bf16(h0))
// ---------------------------------------------------------------------------
__global__ __launch_bounds__(256)
void gru_init(const float* __restrict__ h0, unsigned short* __restrict__ h16,
              int* __restrict__ flags)
{
    int i = blockIdx.x * 256 + threadIdx.x;   // i = b*1024 + j, 65536 total
    int b = i >> 10, j = i & 1023;
    int dst = (b >> 4) * 16384 + (j >> 3) * 128 + (b & 15) * 8 + (j & 7);
    h16[dst] = f2b(h0[i]);
    if (i < 2304) flags[i] = 0;   // 128 h-flags @ 64B stride + 8 chunk counters
}

// ---------------------------------------------------------------------------
// Kernel F: FUSED producer-consumer. Cooperative 256 blocks x 512 threads.
//   bid <  128 : scan role — byte-identical r11 datapath + chunk gate.
//   bid >= 128 : GEMM worker — 96 tile-jobs in s-chunk-major order;
//                gi written via sc1 (agent) stores; done[c] += 1 per chunk.
// gi chunk c (steps [128c,128c+128), all b) = 1536 tiles; 12 jobs/worker/chunk.
// Scan gates chunk entry on done[c]==128. No reverse dependency -> no cycle.
// ---------------------------------------------------------------------------
__global__ __launch_bounds__(512, 1)
void gru_fused(float* __restrict__ gi, const unsigned short* __restrict__ XB,
               const unsigned short* __restrict__ WB, const float* __restrict__ bias,
               const float* __restrict__ Whh, const float* __restrict__ h0,
               unsigned short* __restrict__ h16, int* __restrict__ flags,
               float* __restrict__ out)
{
    __shared__ char smem[52224];
    const int t    = threadIdx.x;
    const int lane = t & 63;
    const int wave = t >> 6;          // 0..7
    const int bid  = blockIdx.x;

    if (bid >= 128) {
        // =================== GEMM worker role ===================
        short* As = (short*)smem;              // [128][64] bf16 linear
        short* Bs = (short*)(smem + 16384);
        const int wkr = bid - 128;
        const int lr  = lane >> 3;             // 0..7
        const int lc  = (lane & 7) * 8;        // bf16 col
        const int mb  = (wave & 1) * 64;
        const int nb  = (wave >> 1) * 32;

        for (int kjob = 0; kjob < 96; ++kjob) {
            int j  = wkr + (kjob << 7);
            int sc = j / 1536, r = j - sc * 1536;
            int b  = r / 24,   n = r - b * 24;
            int m0 = b * 1024 + sc * 128;
            int n0 = n * 128;

            f32x4 acc[4][2] = {};
            for (int k0 = 0; k0 < II; k0 += 64) {
                __syncthreads();
                #pragma unroll
                for (int p = 0; p < 2; ++p) {
                    int sg = p * 8 + wave;     // 0..15, wave-uniform
                    const unsigned short* ga = XB + (size_t)(m0 + sg * 8 + lr) * II + k0 + lc;
                    const unsigned short* gb = WB + (size_t)(n0 + sg * 8 + lr) * II + k0 + lc;
                    __builtin_amdgcn_global_load_lds(
                        (const __attribute__((address_space(1))) void*)ga,
                        (__attribute__((address_space(3))) void*)(As + sg * 512), 16, 0, 0);
                    __builtin_amdgcn_global_load_lds(
                        (const __attribute__((address_space(1))) void*)gb,
                        (__attribute__((address_space(3))) void*)(Bs + sg * 512), 16, 0, 0);
                }
                __syncthreads();
                #pragma unroll
                for (int ks = 0; ks < 2; ++ks) {
                    bf16x8 af[4], bf[2];
                    #pragma unroll
                    for (int i = 0; i < 4; ++i)
                        af[i] = *reinterpret_cast<const bf16x8*>(
                            As + (mb + i * 16 + (lane & 15)) * 64 + ks * 32 + (lane >> 4) * 8);
                    #pragma unroll
                    for (int i = 0; i < 2; ++i)
                        bf[i] = *reinterpret_cast<const bf16x8*>(
                            Bs + (nb + i * 16 + (lane & 15)) * 64 + ks * 32 + (lane >> 4) * 8);
                    #pragma unroll
                    for (int mi = 0; mi < 4; ++mi)
                        #pragma unroll
                        for (int ni = 0; ni < 2; ++ni)
                            acc[mi][ni] = __builtin_amdgcn_mfma_f32_16x16x32_bf16(
                                af[mi], bf[ni], acc[mi][ni], 0, 0, 0);
                }
            }
            // epilogue: bias add, sc1 stores (coherence point — cross-XCD fresh)
            #pragma unroll
            for (int ni = 0; ni < 2; ++ni) {
                int ncol = n0 + nb + ni * 16 + (lane & 15);
                float bv = bias[ncol];
                #pragma unroll
                for (int mi = 0; mi < 4; ++mi) {
                    int mrow = m0 + mb + mi * 16 + ((lane >> 4) << 2);
                    #pragma unroll
                    for (int e = 0; e < 4; ++e) {
                        float v = acc[mi][ni][e] + bv;
                        __hip_atomic_store(
                            (unsigned*)(gi + (size_t)(mrow + e) * G3 + ncol),
                            __float_as_uint(v), __ATOMIC_RELAXED,
                            __HIP_MEMORY_SCOPE_AGENT);
                    }
                }
            }
            if ((kjob % 12) == 11) {           // finished this chunk's 12 jobs
                asm volatile("s_waitcnt vmcnt(0)" ::: "memory");
                __syncthreads();               // all threads' stores drained
                if (t == 0)
                    __hip_atomic_fetch_add(&flags[2048 + (sc << 4)], 1,
                                           __ATOMIC_RELAXED, __HIP_MEMORY_SCOPE_AGENT);
            }
        }
        return;
    }

    // =================== scan role (proven r11 datapath) ===================
    auto part = reinterpret_cast<float(*)[6][4][68]>(smem);  // [8][6][4][68]

    const int group = bid & 3;
    const int jb    = bid >> 2;        // 0..31

    bf16x8 wf[4][6];
    #pragma unroll
    for (int kc = 0; kc < 4; ++kc) {
        #pragma unroll
        for (int nt = 0; nt < 6; ++nt) {
            int rowg = (nt >> 1) * HH + jb * 32 + (nt & 1) * 16 + (lane & 15);
            int k    = wave * 128 + kc * 32 + ((lane >> 4) << 3);
            const float4* src = reinterpret_cast<const float4*>(Whh + (size_t)rowg * HH + k);
            float4 f0 = src[0], f1 = src[1];
            bf16x8 w;
            w[0] = (short)f2b(f0.x); w[1] = (short)f2b(f0.y);
            w[2] = (short)f2b(f0.z); w[3] = (short)f2b(f0.w);
            w[4] = (short)f2b(f1.x); w[5] = (short)f2b(f1.y);
            w[6] = (short)f2b(f1.z); w[7] = (short)f2b(f1.w);
            wf[kc][nt] = w;
        }
    }

    const int b_l = t >> 5;
    const int j_l = t & 31;
    const int b_g = (group << 4) + b_l;
    const int j_g = (jb << 5) + j_l;
    float hreg = h0[b_g * HH + j_g];

    const int frag_base = (wave * 16 + (lane >> 4)) * 256 + ((lane & 15) << 4);
    const int prod_off  = ((j_g >> 3) << 8) + (b_l << 4) + ((j_g & 7) << 1);

    const int nt_r = j_l >> 4;
    const int lp   = ((b_l >> 2) << 4) | (j_l & 15);
    const int e_r  = b_l & 3;

    const int poll_fi = ((group << 5) | (wave << 2) | (lane & 3)) << 4;

    for (int s = 0; s < SS; ++s) {
        // chunk gate: gi chunk (s>>7) must be fully produced (8 gates total)
        if ((s & 127) == 0) {
            if (t == 0) {
                while (__hip_atomic_load(&flags[2048 + ((s >> 7) << 4)],
                                         __ATOMIC_RELAXED, __HIP_MEMORY_SCOPE_AGENT) < 128)
                    __builtin_amdgcn_s_sleep(2);
            }
            __syncthreads();
        }

        const int p = s & 1;
        const char* rslab = (const char*)(h16 + (size_t)p * 65536 + group * 16384);
        unsigned short* wslab = h16 + (size_t)(p ^ 1) * 65536 + group * 16384;

        // prefetch gi (sc1: fresh across XCDs; latency overlapped by poll)
        size_t gib = ((size_t)b_g * SS + s) * G3;
        float ir  = __uint_as_float(__hip_atomic_load(
            (const unsigned*)(gi + gib + j_g), __ATOMIC_RELAXED, __HIP_MEMORY_SCOPE_AGENT));
        float iz  = __uint_as_float(__hip_atomic_load(
            (const unsigned*)(gi + gib + HH + j_g), __ATOMIC_RELAXED, __HIP_MEMORY_SCOPE_AGENT));
        float inn = __uint_as_float(__hip_atomic_load(
            (const unsigned*)(gi + gib + 2 * HH + j_g), __ATOMIC_RELAXED, __HIP_MEMORY_SCOPE_AGENT));

        if (s > 0) {
            while (true) {
                int v = __hip_atomic_load(&flags[poll_fi], __ATOMIC_RELAXED,
                                          __HIP_MEMORY_SCOPE_AGENT);
                if (__all(v >= s)) break;
            }
            asm volatile("" ::: "memory");
        }

        unsigned long long hv[8];
        #pragma unroll
        for (int kc = 0; kc < 4; ++kc) {
            const unsigned long long* q =
                (const unsigned long long*)(rslab + frag_base + kc * 1024);
            hv[2 * kc]     = __hip_atomic_load(q,     __ATOMIC_RELAXED,
                                               __HIP_MEMORY_SCOPE_AGENT);
            hv[2 * kc + 1] = __hip_atomic_load(q + 1, __ATOMIC_RELAXED,
                                               __HIP_MEMORY_SCOPE_AGENT);
        }

        f32x4 acc[6] = {};
        #pragma unroll
        for (int kc = 0; kc < 4; ++kc) {
            union { unsigned long long q[2]; bf16x8 v; } u;
            u.q[0] = hv[2 * kc]; u.q[1] = hv[2 * kc + 1];
            #pragma unroll
            for (int nt = 0; nt < 6; ++nt)
                acc[nt] = __builtin_amdgcn_mfma_f32_16x16x32_bf16(u.v, wf[kc][nt], acc[nt], 0, 0, 0);
        }

        #pragma unroll
        for (int nt = 0; nt < 6; ++nt)
            #pragma unroll
            for (int e = 0; e < 4; ++e)
                part[wave][nt][e][lane] = acc[nt][e];
        __syncthreads();   // bar1

        float hr = 0.f, hz = 0.f, hn = 0.f;
        #pragma unroll
        for (int w = 0; w < 8; ++w) {
            hr += part[w][0 + nt_r][e_r][lp];
            hz += part[w][2 + nt_r][e_r][lp];
            hn += part[w][4 + nt_r][e_r][lp];
        }

        float r  = __builtin_amdgcn_rcpf(1.f + __expf(-(ir + hr)));
        float z  = __builtin_amdgcn_rcpf(1.f + __expf(-(iz + hz)));
        float e2 = __expf(2.f * (inn + r * hn));
        float n  = 1.f - 2.f * __builtin_amdgcn_rcpf(e2 + 1.f);
        float hnew = (1.f - z) * n + z * hreg;
        hreg = hnew;

        unsigned short myb = f2b(hnew);
        unsigned pv = (unsigned)__shfl_xor((int)(unsigned)myb, 1);
        if (!(j_l & 1)) {
            unsigned val = ((unsigned)myb) | (pv << 16);
            __hip_atomic_store((unsigned*)((char*)wslab + prod_off), val,
                               __ATOMIC_RELAXED, __HIP_MEMORY_SCOPE_AGENT);
        }

        asm volatile("s_waitcnt vmcnt(0)" ::: "memory");
        __syncthreads();   // bar2
        if (t == 0)
            __hip_atomic_store(&flags[((group << 5) | jb) << 4], s + 1,
                               __ATOMIC_RELAXED, __HIP_MEMORY_SCOPE_AGENT);

        out[((size_t)b_g * SS + s) * HH + j_g] = hnew;
    }

    out[(size_t)BB * SS * HH + (size_t)b_g * HH + j_g] = hreg;
}

// ---------------------------------------------------------------------------
// Fallback (ws too small for xb/wb): old serial inline-convert GEMM + scan.
// ---------------------------------------------------------------------------
template<int GI_BF16>
__global__ __launch_bounds__(256)
void gi_gemm(const float* __restrict__ X, const float* __restrict__ W,
             const float* __restrict__ bias, void* __restrict__ gi_out)
{
    __shared__ short As[128][40];
    __shared__ short Bs[128][40];

    const int t    = threadIdx.x;
    const int lane = t & 63;
    const int wave = t >> 6;
    const int m0   = blockIdx.y * 128;
    const int n0   = blockIdx.x * 128;

    f32x4 acc[4][4] = {};

    for (int k0 = 0; k0 < II; k0 += 32) {
        __syncthreads();
        #pragma unroll
        for (int q = 0; q < 2; ++q) {
            int row = (t >> 2) + 64 * q;
            int col = (t & 3) * 8;
            const float4* ap = reinterpret_cast<const float4*>(X + (size_t)(m0 + row) * II + k0 + col);
            const float4* bp = reinterpret_cast<const float4*>(W + (size_t)(n0 + row) * II + k0 + col);
            float4 a0 = ap[0], a1 = ap[1];
            float4 b0 = bp[0], b1 = bp[1];
            bf16x8 av, bv;
            av[0] = (short)f2b(a0.x); av[1] = (short)f2b(a0.y);
            av[2] = (short)f2b(a0.z); av[3] = (short)f2b(a0.w);
            av[4] = (short)f2b(a1.x); av[5] = (short)f2b(a1.y);
            av[6] = (short)f2b(a1.z); av[7] = (short)f2b(a1.w);
            bv[0] = (short)f2b(b0.x); bv[1] = (short)f2b(b0.y);
            bv[2] = (short)f2b(b0.z); bv[3] = (short)f2b(b0.w);
            bv[4] = (short)f2b(b1.x); bv[5] = (short)f2b(b1.y);
            bv[6] = (short)f2b(b1.z); bv[7] = (short)f2b(b1.w);
            *reinterpret_cast<bf16x8*>(&As[row][col]) = av;
            *reinterpret_cast<bf16x8*>(&Bs[row][col]) = bv;
        }
        __syncthreads();

        const int mb = (wave & 1) * 64;
        const int nb = (wave >> 1) * 64;
        bf16x8 af[4], bf[4];
        #pragma unroll
        for (int i = 0; i < 4; ++i) {
            af[i] = *reinterpret_cast<const bf16x8*>(&As[mb + i * 16 + (lane & 15)][(lane >> 4) * 8]);
            bf[i] = *reinterpret_cast<const bf16x8*>(&Bs[nb + i * 16 + (lane & 15)][(lane >> 4) * 8]);
        }
        #pragma unroll
        for (int mi = 0; mi < 4; ++mi)
            #pragma unroll
            for (int ni = 0; ni < 4; ++ni)
                acc[mi][ni] = __builtin_amdgcn_mfma_f32_16x16x32_bf16(af[mi], bf[ni], acc[mi][ni], 0, 0, 0);
    }

    const int mb = (wave & 1) * 64;
    const int nb = (wave >> 1) * 64;
    #pragma unroll
    for (int ni = 0; ni < 4; ++ni) {
        int ncol = n0 + nb + ni * 16 + (lane & 15);
        float bv = bias[ncol];
        #pragma unroll
        for (int mi = 0; mi < 4; ++mi) {
            int mrow = m0 + mb + mi * 16 + ((lane >> 4) << 2);
            #pragma unroll
            for (int e = 0; e < 4; ++e) {
                float v = acc[mi][ni][e] + bv;
                size_t idx = (size_t)(mrow + e) * G3 + ncol;
                if (GI_BF16) ((unsigned short*)gi_out)[idx] = f2b(v);
                else         ((float*)gi_out)[idx] = v;
            }
        }
    }
}

template<int GI_BF16>
__global__ __launch_bounds__(512, 1)
void gru_scan(const void* __restrict__ gi_v, const float* __restrict__ Whh,
              const float* __restrict__ h0, unsigned short* __restrict__ h16,
              int* __restrict__ flags, float* __restrict__ out)
{
    const int t     = threadIdx.x;
    const int lane  = t & 63;
    const int wave  = t >> 6;
    const int bid   = blockIdx.x;
    const int group = bid & 3;
    const int jb    = bid >> 2;

    __shared__ float part[8][6][4][68];

    bf16x8 wf[4][6];
    #pragma unroll
    for (int kc = 0; kc < 4; ++kc) {
        #pragma unroll
        for (int nt = 0; nt < 6; ++nt) {
            int rowg = (nt >> 1) * HH + jb * 32 + (nt & 1) * 16 + (lane & 15);
            int k    = wave * 128 + kc * 32 + ((lane >> 4) << 3);
            const float4* src = reinterpret_cast<const float4*>(Whh + (size_t)rowg * HH + k);
            float4 f0 = src[0], f1 = src[1];
            bf16x8 w;
            w[0] = (short)f2b(f0.x); w[1] = (short)f2b(f0.y);
            w[2] = (short)f2b(f0.z); w[3] = (short)f2b(f0.w);
            w[4] = (short)f2b(f1.x); w[5] = (short)f2b(f1.y);
            w[6] = (short)f2b(f1.z); w[7] = (short)f2b(f1.w);
            wf[kc][nt] = w;
        }
    }

    const int b_l = t >> 5;
    const int j_l = t & 31;
    const int b_g = (group << 4) + b_l;
    const int j_g = (jb << 5) + j_l;
    float hreg = h0[b_g * HH + j_g];

    const int frag_base = (wave * 16 + (lane >> 4)) * 256 + ((lane & 15) << 4);
    const int prod_off  = ((j_g >> 3) << 8) + (b_l << 4) + ((j_g & 7) << 1);

    const int nt_r = j_l >> 4;
    const int lp   = ((b_l >> 2) << 4) | (j_l & 15);
    const int e_r  = b_l & 3;

    const int poll_fi = ((group << 5) | (wave << 2) | (lane & 3)) << 4;

    for (int s = 0; s < SS; ++s) {
        const int p = s & 1;
        const char* rslab = (const char*)(h16 + (size_t)p * 65536 + group * 16384);
        unsigned short* wslab = h16 + (size_t)(p ^ 1) * 65536 + group * 16384;

        size_t gib = ((size_t)b_g * SS + s) * G3;
        float ir, iz, inn;
        if (GI_BF16) {
            const unsigned short* g16 = (const unsigned short*)gi_v;
            ir  = b2f(g16[gib + j_g]);
            iz  = b2f(g16[gib + HH + j_g]);
            inn = b2f(g16[gib + 2 * HH + j_g]);
        } else {
            const float* g32 = (const float*)gi_v;
            ir  = g32[gib + j_g];
            iz  = g32[gib + HH + j_g];
            inn = g32[gib + 2 * HH + j_g];
        }

        if (s > 0) {
            while (true) {
                int v = __hip_atomic_load(&flags[poll_fi], __ATOMIC_RELAXED,
                                          __HIP_MEMORY_SCOPE_AGENT);
                if (__all(v >= s)) break;
            }
            asm volatile("" ::: "memory");
        }

        unsigned long long hv[8];
        #pragma unroll
        for (int kc = 0; kc < 4; ++kc) {
            const unsigned long long* q =
                (const unsigned long long*)(rslab + frag_base + kc * 1024);
            hv[2 * kc]     = __hip_atomic_load(q,     __ATOMIC_RELAXED,
                                               __HIP_MEMORY_SCOPE_AGENT);
            hv[2 * kc + 1] = __hip_atomic_load(q + 1, __ATOMIC_RELAXED,
                                               __HIP_MEMORY_SCOPE_AGENT);
        }

        f32x4 acc[6] = {};
        #pragma unroll
        for (int kc = 0; kc < 4; ++kc) {
            union { unsigned long long q[2]; bf16x8 v; } u;
            u.q[0] = hv[2 * kc]; u.q[1] = hv[2 * kc + 1];
            #pragma unroll
            for (int nt = 0; nt < 6; ++nt)
                acc[nt] = __builtin_amdgcn_mfma_f32_16x16x32_bf16(u.v, wf[kc][nt], acc[nt], 0, 0, 0);
        }

        #pragma unroll
        for (int nt = 0; nt < 6; ++nt)
            #pragma unroll
            for (int e = 0; e < 4; ++e)
                part[wave][nt][e][lane] = acc[nt][e];
        __syncthreads();

        float hr = 0.f, hz = 0.f, hn = 0.f;
        #pragma unroll
        for (int w = 0; w < 8; ++w) {
            hr += part[w][0 + nt_r][e_r][lp];
            hz += part[w][2 + nt_r][e_r][lp];
            hn += part[w][4 + nt_r][e_r][lp];
        }

        float r  = __builtin_amdgcn_rcpf(1.f + __expf(-(ir + hr)));
        float z  = __builtin_amdgcn_rcpf(1.f + __expf(-(iz + hz)));
        float e2 = __expf(2.f * (inn + r * hn));
        float n  = 1.f - 2.f * __builtin_amdgcn_rcpf(e2 + 1.f);
        float hnew = (1.f - z) * n + z * hreg;
        hreg = hnew;

        unsigned short myb = f2b(hnew);
        unsigned pv = (unsigned)__shfl_xor((int)(unsigned)myb, 1);
        if (!(j_l & 1)) {
            unsigned val = ((unsigned)myb) | (pv << 16);
            __hip_atomic_store((unsigned*)((char*)wslab + prod_off), val,
                               __ATOMIC_RELAXED, __HIP_MEMORY_SCOPE_AGENT);
        }

        asm volatile("s_waitcnt vmcnt(0)" ::: "memory");
        __syncthreads();
        if (t == 0)
            __hip_atomic_store(&flags[((group << 5) | jb) << 4], s + 1,
                               __ATOMIC_RELAXED, __HIP_MEMORY_SCOPE_AGENT);

        out[((size_t)b_g * SS + s) * HH + j_g] = hnew;
    }

    out[(size_t)BB * SS * HH + (size_t)b_g * HH + j_g] = hreg;
}

// ---------------------------------------------------------------------------
// Host launcher
// ---------------------------------------------------------------------------
extern "C" void kernel_launch(void* const* d_in, const int* in_sizes, int n_in,
                              void* d_out, int out_size, void* d_ws, size_t ws_size,
                              hipStream_t stream)
{
    const float* x   = (const float*)d_in[0];
    const float* h0  = (const float*)d_in[1];
    const float* Wih = (const float*)d_in[2];
    const float* Whh = (const float*)d_in[3];
    const float* bih = (const float*)d_in[4];
    float* out = (float*)d_out;

    char* ws = (char*)d_ws;
    unsigned short* h16 = (unsigned short*)ws;               // 2 x 128KiB parity bufs
    int* flags          = (int*)(ws + 262144);               // h-flags + chunk ctrs
    void* gi            = (void*)(ws + (1 << 20));           // 1 MiB offset

    const size_t gi32_bytes = (size_t)BB * SS * G3 * 4;      // 768 MiB
    const size_t gi16_bytes = gi32_bytes / 2;                // 384 MiB
    const size_t xb_off   = (size_t)(1 << 20) + gi32_bytes;
    const size_t wb_off   = xb_off + (size_t)BB * SS * II * 2;
    const size_t need_new = wb_off + (size_t)G3 * II * 2;

    const bool use_new = ws_size >= need_new;
    const bool use_f32 = !use_new && ws_size >= ((size_t)(1 << 20) + gi32_bytes);
    const bool use_b16 = !use_new && !use_f32 &&
                         ws_size >= ((size_t)(1 << 20) + gi16_bytes);
    if (!use_new && !use_f32 && !use_b16) return;

    gru_init<<<dim3(256), dim3(256), 0, stream>>>(h0, h16, flags);

    if (use_new) {
        unsigned short* xb = (unsigned short*)(ws + xb_off);
        unsigned short* wb = (unsigned short*)(ws + wb_off);
        conv_b16<<<dim3(68608), dim3(256), 0, stream>>>(x, Wih, xb, wb);
        float* gi_f = (float*)gi;
        const unsigned short* xb_c = xb;
        const unsigned short* wb_c = wb;
        const float* bih_c = bih;
        const float* Whh_c = Whh;
        const float* h0_c = h0;
        unsigned short* h16_c = h16;
        int* flags_c = flags;
        float* out_c = out;
        void* args[] = { (void*)&gi_f, (void*)&xb_c, (void*)&wb_c, (void*)&bih_c,
                         (void*)&Whh_c, (void*)&h0_c, (void*)&h16_c,
                         (void*)&flags_c, (void*)&out_c };
        hipLaunchCooperativeKernel((const void*)&gru_fused, dim3(256), dim3(512),
                                   args, 0, stream);
    } else {
        const void* gi_c = gi;
        const float* Whh_c = Whh;
        const float* h0_c = h0;
        unsigned short* h16_c = h16;
        int* flags_c = flags;
        float* out_c = out;
        void* args[] = { (void*)&gi_c, (void*)&Whh_c, (void*)&h0_c,
                         (void*)&h16_c, (void*)&flags_c, (void*)&out_c };
        if (use_f32) {
            gi_gemm<0><<<dim3(24, 512), dim3(256), 0, stream>>>(x, Wih, bih, gi);
            hipLaunchCooperativeKernel((const void*)&gru_scan<0>, dim3(128), dim3(512),
                                       args, 0, stream);
        } else {
            gi_gemm<1><<<dim3(24, 512), dim3(256), 0, stream>>>(x, Wih, bih, gi);
            hipLaunchCooperativeKernel((const void*)&gru_scan<1>, dim3(128), dim3(512),
                                       args, 0, stream);
        }
    }
}

// Round 14
// 2985.285 us; speedup vs baseline: 2.3002x; 1.1343x over previous
//
#include <hip/hip_runtime.h>
#include <hip/hip_bf16.h>
#include <cstdint>
#include <cstddef>

// Problem sizes (fixed)
#define BB 64
#define SS 1024
#define II 1024
#define HH 1024
#define G3 3072   // 3*HH

typedef float  f32x4  __attribute__((ext_vector_type(4)));
typedef short  bf16x8 __attribute__((ext_vector_type(8)));

__device__ __forceinline__ unsigned short f2b(float f) {
    unsigned u = __float_as_uint(f);
    u += 0x7FFFu + ((u >> 16) & 1u);   // RNE
    return (unsigned short)(u >> 16);
}
__device__ __forceinline__ float b2f(unsigned short s) {
    return __uint_as_float(((unsigned)s) << 16);
}

// ---------------------------------------------------------------------------
// Kernel 0: bf16 prepass — xb = bf16(x), wb = bf16(W_ih). One pass, HBM-bound.
// ---------------------------------------------------------------------------
__global__ __launch_bounds__(256)
void conv_b16(const float* __restrict__ x, const float* __restrict__ w,
              unsigned short* __restrict__ xb, unsigned short* __restrict__ wb)
{
    const size_t XN = (size_t)BB * SS * II;     // 67108864
    const size_t WN = (size_t)G3 * II;          // 3145728
    size_t i = ((size_t)blockIdx.x * 256 + threadIdx.x) * 4;
    if (i < XN) {
        float4 v = *reinterpret_cast<const float4*>(x + i);
        uint2 p;
        p.x = (unsigned)f2b(v.x) | ((unsigned)f2b(v.y) << 16);
        p.y = (unsigned)f2b(v.z) | ((unsigned)f2b(v.w) << 16);
        *reinterpret_cast<uint2*>(xb + i) = p;
    } else {
        size_t j = i - XN;
        if (j < WN) {
            float4 v = *reinterpret_cast<const float4*>(w + j);
            uint2 p;
            p.x = (unsigned)f2b(v.x) | ((unsigned)f2b(v.y) << 16);
            p.y = (unsigned)f2b(v.z) | ((unsigned)f2b(v.w) << 16);
            *reinterpret_cast<uint2*>(wb + j) = p;
        }
    }
}

// ---------------------------------------------------------------------------
// Kernel 2: init  (reset flags + chunk counters, h16[buf0] = bf16(h0))
// ---------------------------------------------------------------------------
__global__ __launch_bounds__(256)
void gru_init(const float* __restrict__ h0, unsigned short* __restrict__ h16,
              int* __restrict__ flags)
{
    int i = blockIdx.x * 256 + threadIdx.x;   // i = b*1024 + j, 65536 total
    int b = i >> 10, j = i & 1023;
    int dst = (b >> 4) * 16384 + (j >> 3) * 128 + (b & 15) * 8 + (j & 7);
    h16[dst] = f2b(h0[i]);
    if (i < 2304) flags[i] = 0;   // 128 h-flags @ 64B stride + 8 chunk counters
}

// ---------------------------------------------------------------------------
// One 128x128 GEMM tile job: gi16[m0..m0+128, n0..n0+128) = xb @ wb^T + bias,
// written as packed bf16 pairs via sc1 (agent) stores. Called by all 512
// threads of a block; uses As/Bs (32KB) of smem.
// ---------------------------------------------------------------------------
__device__ __forceinline__ void gemm_tile(
    const unsigned short* __restrict__ XB, const unsigned short* __restrict__ WB,
    const float* __restrict__ bias, unsigned short* __restrict__ gi16,
    short* As, short* Bs, int m0, int n0, int t, int lane, int wave)
{
    const int lr = lane >> 3;             // 0..7
    const int lc = (lane & 7) * 8;        // bf16 col
    const int mb = (wave & 1) * 64;
    const int nb = (wave >> 1) * 32;

    f32x4 acc[4][2] = {};
    for (int k0 = 0; k0 < II; k0 += 64) {
        __syncthreads();
        #pragma unroll
        for (int p = 0; p < 2; ++p) {
            int sg = p * 8 + wave;        // 0..15, wave-uniform
            const unsigned short* ga = XB + (size_t)(m0 + sg * 8 + lr) * II + k0 + lc;
            const unsigned short* gb = WB + (size_t)(n0 + sg * 8 + lr) * II + k0 + lc;
            __builtin_amdgcn_global_load_lds(
                (const __attribute__((address_space(1))) void*)ga,
                (__attribute__((address_space(3))) void*)(As + sg * 512), 16, 0, 0);
            __builtin_amdgcn_global_load_lds(
                (const __attribute__((address_space(1))) void*)gb,
                (__attribute__((address_space(3))) void*)(Bs + sg * 512), 16, 0, 0);
        }
        __syncthreads();
        #pragma unroll
        for (int ks = 0; ks < 2; ++ks) {
            bf16x8 af[4], bf[2];
            #pragma unroll
            for (int i = 0; i < 4; ++i)
                af[i] = *reinterpret_cast<const bf16x8*>(
                    As + (mb + i * 16 + (lane & 15)) * 64 + ks * 32 + (lane >> 4) * 8);
            #pragma unroll
            for (int i = 0; i < 2; ++i)
                bf[i] = *reinterpret_cast<const bf16x8*>(
                    Bs + (nb + i * 16 + (lane & 15)) * 64 + ks * 32 + (lane >> 4) * 8);
            #pragma unroll
            for (int mi = 0; mi < 4; ++mi)
                #pragma unroll
                for (int ni = 0; ni < 2; ++ni)
                    acc[mi][ni] = __builtin_amdgcn_mfma_f32_16x16x32_bf16(
                        af[mi], bf[ni], acc[mi][ni], 0, 0, 0);
        }
    }
    // epilogue: bias add, bf16 pack across lane pairs, sc1 u32 stores
    #pragma unroll
    for (int ni = 0; ni < 2; ++ni) {
        int ncol = n0 + nb + ni * 16 + (lane & 15);
        float bv = bias[ncol];
        #pragma unroll
        for (int mi = 0; mi < 4; ++mi) {
            int mrow = m0 + mb + mi * 16 + ((lane >> 4) << 2);
            #pragma unroll
            for (int e = 0; e < 4; ++e) {
                float v = acc[mi][ni][e] + bv;
                unsigned short hb = f2b(v);
                unsigned pv = (unsigned)__shfl_xor((int)(unsigned)hb, 1);
                if (!(lane & 1)) {
                    unsigned word = (unsigned)hb | (pv << 16);
                    __hip_atomic_store(
                        (unsigned*)(gi16 + (size_t)(mrow + e) * G3 + ncol),
                        word, __ATOMIC_RELAXED, __HIP_MEMORY_SCOPE_AGENT);
                }
            }
        }
    }
}

// ---------------------------------------------------------------------------
// Kernel F: FUSED producer-consumer. Cooperative 256 blocks x 512 threads.
// Phase 0 (ALL blocks): 6 chunk-0 tiles each (256*6 = 1536 = whole chunk 0)
//   -> done[0] += 1 (target 256). Halves the priming delay.
// Then bid<128: scan role (proven r11 datapath, bf16 gi reads, chunk gates);
//      bid>=128: worker role — chunks 1..7, 12 jobs each -> done[c] += 1.
// ---------------------------------------------------------------------------
__global__ __launch_bounds__(512, 1)
void gru_fused(unsigned short* __restrict__ gi16,
               const unsigned short* __restrict__ XB,
               const unsigned short* __restrict__ WB, const float* __restrict__ bias,
               const float* __restrict__ Whh, const float* __restrict__ h0,
               unsigned short* __restrict__ h16, int* __restrict__ flags,
               float* __restrict__ out)
{
    __shared__ char smem[52224];
    const int t    = threadIdx.x;
    const int lane = t & 63;
    const int wave = t >> 6;          // 0..7
    const int bid  = blockIdx.x;

    short* As = (short*)smem;
    short* Bs = (short*)(smem + 16384);

    // ---- phase 0: all 256 blocks produce chunk 0 (tiles bid*6 .. bid*6+5) ----
    #pragma unroll 1
    for (int q = 0; q < 6; ++q) {
        int tile = bid * 6 + q;          // 0..1535
        int b = tile / 24, n = tile % 24;
        gemm_tile(XB, WB, bias, gi16, As, Bs, b * 1024, n * 128, t, lane, wave);
    }
    asm volatile("s_waitcnt vmcnt(0)" ::: "memory");
    __syncthreads();                     // all sc1 stores drained, smem free
    if (t == 0)
        __hip_atomic_fetch_add(&flags[2048], 1,
                               __ATOMIC_RELAXED, __HIP_MEMORY_SCOPE_AGENT);

    if (bid >= 128) {
        // =================== worker role: chunks 1..7 ===================
        const int wkr = bid - 128;
        #pragma unroll 1
        for (int jj = 0; jj < 84; ++jj) {
            int c   = 1 + jj / 12;
            int idx = (jj % 12) * 128 + wkr;     // 0..1535 within chunk
            int b = idx / 24, n = idx % 24;
            gemm_tile(XB, WB, bias, gi16, As, Bs,
                      b * 1024 + c * 128, n * 128, t, lane, wave);
            if ((jj % 12) == 11) {
                asm volatile("s_waitcnt vmcnt(0)" ::: "memory");
                __syncthreads();
                if (t == 0)
                    __hip_atomic_fetch_add(&flags[2048 + (c << 4)], 1,
                                           __ATOMIC_RELAXED, __HIP_MEMORY_SCOPE_AGENT);
            }
        }
        return;
    }

    // =================== scan role (proven r11 datapath) ===================
    auto part = reinterpret_cast<float(*)[6][4][68]>(smem);  // [8][6][4][68]

    const int group = bid & 3;
    const int jb    = bid >> 2;        // 0..31

    bf16x8 wf[4][6];
    #pragma unroll
    for (int kc = 0; kc < 4; ++kc) {
        #pragma unroll
        for (int nt = 0; nt < 6; ++nt) {
            int rowg = (nt >> 1) * HH + jb * 32 + (nt & 1) * 16 + (lane & 15);
            int k    = wave * 128 + kc * 32 + ((lane >> 4) << 3);
            const float4* src = reinterpret_cast<const float4*>(Whh + (size_t)rowg * HH + k);
            float4 f0 = src[0], f1 = src[1];
            bf16x8 w;
            w[0] = (short)f2b(f0.x); w[1] = (short)f2b(f0.y);
            w[2] = (short)f2b(f0.z); w[3] = (short)f2b(f0.w);
            w[4] = (short)f2b(f1.x); w[5] = (short)f2b(f1.y);
            w[6] = (short)f2b(f1.z); w[7] = (short)f2b(f1.w);
            wf[kc][nt] = w;
        }
    }

    const int b_l = t >> 5;
    const int j_l = t & 31;
    const int b_g = (group << 4) + b_l;
    const int j_g = (jb << 5) + j_l;
    float hreg = h0[b_g * HH + j_g];

    const int frag_base = (wave * 16 + (lane >> 4)) * 256 + ((lane & 15) << 4);
    const int prod_off  = ((j_g >> 3) << 8) + (b_l << 4) + ((j_g & 7) << 1);

    const int nt_r = j_l >> 4;
    const int lp   = ((b_l >> 2) << 4) | (j_l & 15);
    const int e_r  = b_l & 3;

    const int poll_fi = ((group << 5) | (wave << 2) | (lane & 3)) << 4;
    const int jeven = j_g & ~1;
    const int jsel  = (j_g & 1) << 4;   // 0 or 16 bit shift

    for (int s = 0; s < SS; ++s) {
        // chunk gate: gi chunk (s>>7) fully produced (chunk0 target 256)
        if ((s & 127) == 0) {
            const int target = (s == 0) ? 256 : 128;
            if (t == 0) {
                while (__hip_atomic_load(&flags[2048 + ((s >> 7) << 4)],
                                         __ATOMIC_RELAXED, __HIP_MEMORY_SCOPE_AGENT) < target)
                    __builtin_amdgcn_s_sleep(2);
            }
            __syncthreads();
        }

        const int p = s & 1;
        const char* rslab = (const char*)(h16 + (size_t)p * 65536 + group * 16384);
        unsigned short* wslab = h16 + (size_t)(p ^ 1) * 65536 + group * 16384;

        // prefetch gi (bf16 pairs, sc1: fresh across XCDs)
        size_t gib = ((size_t)b_g * SS + s) * G3;
        unsigned wr = __hip_atomic_load((const unsigned*)(gi16 + gib + jeven),
                                        __ATOMIC_RELAXED, __HIP_MEMORY_SCOPE_AGENT);
        unsigned wz = __hip_atomic_load((const unsigned*)(gi16 + gib + HH + jeven),
                                        __ATOMIC_RELAXED, __HIP_MEMORY_SCOPE_AGENT);
        unsigned wn = __hip_atomic_load((const unsigned*)(gi16 + gib + 2 * HH + jeven),
                                        __ATOMIC_RELAXED, __HIP_MEMORY_SCOPE_AGENT);
        float ir  = b2f((unsigned short)(wr >> jsel));
        float iz  = b2f((unsigned short)(wz >> jsel));
        float inn = b2f((unsigned short)(wn >> jsel));

        if (s > 0) {
            while (true) {
                int v = __hip_atomic_load(&flags[poll_fi], __ATOMIC_RELAXED,
                                          __HIP_MEMORY_SCOPE_AGENT);
                if (__all(v >= s)) break;
            }
            asm volatile("" ::: "memory");
        }

        unsigned long long hv[8];
        #pragma unroll
        for (int kc = 0; kc < 4; ++kc) {
            const unsigned long long* q =
                (const unsigned long long*)(rslab + frag_base + kc * 1024);
            hv[2 * kc]     = __hip_atomic_load(q,     __ATOMIC_RELAXED,
                                               __HIP_MEMORY_SCOPE_AGENT);
            hv[2 * kc + 1] = __hip_atomic_load(q + 1, __ATOMIC_RELAXED,
                                               __HIP_MEMORY_SCOPE_AGENT);
        }

        f32x4 acc[6] = {};
        #pragma unroll
        for (int kc = 0; kc < 4; ++kc) {
            union { unsigned long long q[2]; bf16x8 v; } u;
            u.q[0] = hv[2 * kc]; u.q[1] = hv[2 * kc + 1];
            #pragma unroll
            for (int nt = 0; nt < 6; ++nt)
                acc[nt] = __builtin_amdgcn_mfma_f32_16x16x32_bf16(u.v, wf[kc][nt], acc[nt], 0, 0, 0);
        }

        #pragma unroll
        for (int nt = 0; nt < 6; ++nt)
            #pragma unroll
            for (int e = 0; e < 4; ++e)
                part[wave][nt][e][lane] = acc[nt][e];
        __syncthreads();   // bar1

        float hr = 0.f, hz = 0.f, hn = 0.f;
        #pragma unroll
        for (int w = 0; w < 8; ++w) {
            hr += part[w][0 + nt_r][e_r][lp];
            hz += part[w][2 + nt_r][e_r][lp];
            hn += part[w][4 + nt_r][e_r][lp];
        }

        float r  = __builtin_amdgcn_rcpf(1.f + __expf(-(ir + hr)));
        float z  = __builtin_amdgcn_rcpf(1.f + __expf(-(iz + hz)));
        float e2 = __expf(2.f * (inn + r * hn));
        float n  = 1.f - 2.f * __builtin_amdgcn_rcpf(e2 + 1.f);
        float hnew = (1.f - z) * n + z * hreg;
        hreg = hnew;

        unsigned short myb = f2b(hnew);
        unsigned pv = (unsigned)__shfl_xor((int)(unsigned)myb, 1);
        if (!(j_l & 1)) {
            unsigned val = ((unsigned)myb) | (pv << 16);
            __hip_atomic_store((unsigned*)((char*)wslab + prod_off), val,
                               __ATOMIC_RELAXED, __HIP_MEMORY_SCOPE_AGENT);
        }

        asm volatile("s_waitcnt vmcnt(0)" ::: "memory");
        __syncthreads();   // bar2
        if (t == 0)
            __hip_atomic_store(&flags[((group << 5) | jb) << 4], s + 1,
                               __ATOMIC_RELAXED, __HIP_MEMORY_SCOPE_AGENT);

        out[((size_t)b_g * SS + s) * HH + j_g] = hnew;
    }

    out[(size_t)BB * SS * HH + (size_t)b_g * HH + j_g] = hreg;
}

// ---------------------------------------------------------------------------
// Fallback (ws too small for xb/wb): old serial inline-convert GEMM + scan.
// ---------------------------------------------------------------------------
template<int GI_BF16>
__global__ __launch_bounds__(256)
void gi_gemm(const float* __restrict__ X, const float* __restrict__ W,
             const float* __restrict__ bias, void* __restrict__ gi_out)
{
    __shared__ short As[128][40];
    __shared__ short Bs[128][40];

    const int t    = threadIdx.x;
    const int lane = t & 63;
    const int wave = t >> 6;
    const int m0   = blockIdx.y * 128;
    const int n0   = blockIdx.x * 128;

    f32x4 acc[4][4] = {};

    for (int k0 = 0; k0 < II; k0 += 32) {
        __syncthreads();
        #pragma unroll
        for (int q = 0; q < 2; ++q) {
            int row = (t >> 2) + 64 * q;
            int col = (t & 3) * 8;
            const float4* ap = reinterpret_cast<const float4*>(X + (size_t)(m0 + row) * II + k0 + col);
            const float4* bp = reinterpret_cast<const float4*>(W + (size_t)(n0 + row) * II + k0 + col);
            float4 a0 = ap[0], a1 = ap[1];
            float4 b0 = bp[0], b1 = bp[1];
            bf16x8 av, bv;
            av[0] = (short)f2b(a0.x); av[1] = (short)f2b(a0.y);
            av[2] = (short)f2b(a0.z); av[3] = (short)f2b(a0.w);
            av[4] = (short)f2b(a1.x); av[5] = (short)f2b(a1.y);
            av[6] = (short)f2b(a1.z); av[7] = (short)f2b(a1.w);
            bv[0] = (short)f2b(b0.x); bv[1] = (short)f2b(b0.y);
            bv[2] = (short)f2b(b0.z); bv[3] = (short)f2b(b0.w);
            bv[4] = (short)f2b(b1.x); bv[5] = (short)f2b(b1.y);
            bv[6] = (short)f2b(b1.z); bv[7] = (short)f2b(b1.w);
            *reinterpret_cast<bf16x8*>(&As[row][col]) = av;
            *reinterpret_cast<bf16x8*>(&Bs[row][col]) = bv;
        }
        __syncthreads();

        const int mb = (wave & 1) * 64;
        const int nb = (wave >> 1) * 64;
        bf16x8 af[4], bf[4];
        #pragma unroll
        for (int i = 0; i < 4; ++i) {
            af[i] = *reinterpret_cast<const bf16x8*>(&As[mb + i * 16 + (lane & 15)][(lane >> 4) * 8]);
            bf[i] = *reinterpret_cast<const bf16x8*>(&Bs[nb + i * 16 + (lane & 15)][(lane >> 4) * 8]);
        }
        #pragma unroll
        for (int mi = 0; mi < 4; ++mi)
            #pragma unroll
            for (int ni = 0; ni < 4; ++ni)
                acc[mi][ni] = __builtin_amdgcn_mfma_f32_16x16x32_bf16(af[mi], bf[ni], acc[mi][ni], 0, 0, 0);
    }

    const int mb = (wave & 1) * 64;
    const int nb = (wave >> 1) * 64;
    #pragma unroll
    for (int ni = 0; ni < 4; ++ni) {
        int ncol = n0 + nb + ni * 16 + (lane & 15);
        float bv = bias[ncol];
        #pragma unroll
        for (int mi = 0; mi < 4; ++mi) {
            int mrow = m0 + mb + mi * 16 + ((lane >> 4) << 2);
            #pragma unroll
            for (int e = 0; e < 4; ++e) {
                float v = acc[mi][ni][e] + bv;
                size_t idx = (size_t)(mrow + e) * G3 + ncol;
                if (GI_BF16) ((unsigned short*)gi_out)[idx] = f2b(v);
                else         ((float*)gi_out)[idx] = v;
            }
        }
    }
}

template<int GI_BF16>
__global__ __launch_bounds__(512, 1)
void gru_scan(const void* __restrict__ gi_v, const float* __restrict__ Whh,
              const float* __restrict__ h0, unsigned short* __restrict__ h16,
              int* __restrict__ flags, float* __restrict__ out)
{
    const int t     = threadIdx.x;
    const int lane  = t & 63;
    const int wave  = t >> 6;
    const int bid   = blockIdx.x;
    const int group = bid & 3;
    const int jb    = bid >> 2;

    __shared__ float part[8][6][4][68];

    bf16x8 wf[4][6];
    #pragma unroll
    for (int kc = 0; kc < 4; ++kc) {
        #pragma unroll
        for (int nt = 0; nt < 6; ++nt) {
            int rowg = (nt >> 1) * HH + jb * 32 + (nt & 1) * 16 + (lane & 15);
            int k    = wave * 128 + kc * 32 + ((lane >> 4) << 3);
            const float4* src = reinterpret_cast<const float4*>(Whh + (size_t)rowg * HH + k);
            float4 f0 = src[0], f1 = src[1];
            bf16x8 w;
            w[0] = (short)f2b(f0.x); w[1] = (short)f2b(f0.y);
            w[2] = (short)f2b(f0.z); w[3] = (short)f2b(f0.w);
            w[4] = (short)f2b(f1.x); w[5] = (short)f2b(f1.y);
            w[6] = (short)f2b(f1.z); w[7] = (short)f2b(f1.w);
            wf[kc][nt] = w;
        }
    }

    const int b_l = t >> 5;
    const int j_l = t & 31;
    const int b_g = (group << 4) + b_l;
    const int j_g = (jb << 5) + j_l;
    float hreg = h0[b_g * HH + j_g];

    const int frag_base = (wave * 16 + (lane >> 4)) * 256 + ((lane & 15) << 4);
    const int prod_off  = ((j_g >> 3) << 8) + (b_l << 4) + ((j_g & 7) << 1);

    const int nt_r = j_l >> 4;
    const int lp   = ((b_l >> 2) << 4) | (j_l & 15);
    const int e_r  = b_l & 3;

    const int poll_fi = ((group << 5) | (wave << 2) | (lane & 3)) << 4;

    for (int s = 0; s < SS; ++s) {
        const int p = s & 1;
        const char* rslab = (const char*)(h16 + (size_t)p * 65536 + group * 16384);
        unsigned short* wslab = h16 + (size_t)(p ^ 1) * 65536 + group * 16384;

        size_t gib = ((size_t)b_g * SS + s) * G3;
        float ir, iz, inn;
        if (GI_BF16) {
            const unsigned short* g16 = (const unsigned short*)gi_v;
            ir  = b2f(g16[gib + j_g]);
            iz  = b2f(g16[gib + HH + j_g]);
            inn = b2f(g16[gib + 2 * HH + j_g]);
        } else {
            const float* g32 = (const float*)gi_v;
            ir  = g32[gib + j_g];
            iz  = g32[gib + HH + j_g];
            inn = g32[gib + 2 * HH + j_g];
        }

        if (s > 0) {
            while (true) {
                int v = __hip_atomic_load(&flags[poll_fi], __ATOMIC_RELAXED,
                                          __HIP_MEMORY_SCOPE_AGENT);
                if (__all(v >= s)) break;
            }
            asm volatile("" ::: "memory");
        }

        unsigned long long hv[8];
        #pragma unroll
        for (int kc = 0; kc < 4; ++kc) {
            const unsigned long long* q =
                (const unsigned long long*)(rslab + frag_base + kc * 1024);
            hv[2 * kc]     = __hip_atomic_load(q,     __ATOMIC_RELAXED,
                                               __HIP_MEMORY_SCOPE_AGENT);
            hv[2 * kc + 1] = __hip_atomic_load(q + 1, __ATOMIC_RELAXED,
                                               __HIP_MEMORY_SCOPE_AGENT);
        }

        f32x4 acc[6] = {};
        #pragma unroll
        for (int kc = 0; kc < 4; ++kc) {
            union { unsigned long long q[2]; bf16x8 v; } u;
            u.q[0] = hv[2 * kc]; u.q[1] = hv[2 * kc + 1];
            #pragma unroll
            for (int nt = 0; nt < 6; ++nt)
                acc[nt] = __builtin_amdgcn_mfma_f32_16x16x32_bf16(u.v, wf[kc][nt], acc[nt], 0, 0, 0);
        }

        #pragma unroll
        for (int nt = 0; nt < 6; ++nt)
            #pragma unroll
            for (int e = 0; e < 4; ++e)
                part[wave][nt][e][lane] = acc[nt][e];
        __syncthreads();

        float hr = 0.f, hz = 0.f, hn = 0.f;
        #pragma unroll
        for (int w = 0; w < 8; ++w) {
            hr += part[w][0 + nt_r][e_r][lp];
            hz += part[w][2 + nt_r][e_r][lp];
            hn += part[w][4 + nt_r][e_r][lp];
        }

        float r  = __builtin_amdgcn_rcpf(1.f + __expf(-(ir + hr)));
        float z  = __builtin_amdgcn_rcpf(1.f + __expf(-(iz + hz)));
        float e2 = __expf(2.f * (inn + r * hn));
        float n  = 1.f - 2.f * __builtin_amdgcn_rcpf(e2 + 1.f);
        float hnew = (1.f - z) * n + z * hreg;
        hreg = hnew;

        unsigned short myb = f2b(hnew);
        unsigned pv = (unsigned)__shfl_xor((int)(unsigned)myb, 1);
        if (!(j_l & 1)) {
            unsigned val = ((unsigned)myb) | (pv << 16);
            __hip_atomic_store((unsigned*)((char*)wslab + prod_off), val,
                               __ATOMIC_RELAXED, __HIP_MEMORY_SCOPE_AGENT);
        }

        asm volatile("s_waitcnt vmcnt(0)" ::: "memory");
        __syncthreads();
        if (t == 0)
            __hip_atomic_store(&flags[((group << 5) | jb) << 4], s + 1,
                               __ATOMIC_RELAXED, __HIP_MEMORY_SCOPE_AGENT);

        out[((size_t)b_g * SS + s) * HH + j_g] = hnew;
    }

    out[(size_t)BB * SS * HH + (size_t)b_g * HH + j_g] = hreg;
}

// ---------------------------------------------------------------------------
// Host launcher
// ---------------------------------------------------------------------------
extern "C" void kernel_launch(void* const* d_in, const int* in_sizes, int n_in,
                              void* d_out, int out_size, void* d_ws, size_t ws_size,
                              hipStream_t stream)
{
    const float* x   = (const float*)d_in[0];
    const float* h0  = (const float*)d_in[1];
    const float* Wih = (const float*)d_in[2];
    const float* Whh = (const float*)d_in[3];
    const float* bih = (const float*)d_in[4];
    float* out = (float*)d_out;

    char* ws = (char*)d_ws;
    unsigned short* h16 = (unsigned short*)ws;               // 2 x 128KiB parity bufs
    int* flags          = (int*)(ws + 262144);               // h-flags + chunk ctrs
    void* gi            = (void*)(ws + (1 << 20));           // 1 MiB offset

    const size_t gi32_bytes = (size_t)BB * SS * G3 * 4;      // 768 MiB
    const size_t gi16_bytes = gi32_bytes / 2;                // 384 MiB
    const size_t xb_off   = (size_t)(1 << 20) + gi32_bytes;
    const size_t wb_off   = xb_off + (size_t)BB * SS * II * 2;
    const size_t need_new = wb_off + (size_t)G3 * II * 2;

    const bool use_new = ws_size >= need_new;
    const bool use_f32 = !use_new && ws_size >= ((size_t)(1 << 20) + gi32_bytes);
    const bool use_b16 = !use_new && !use_f32 &&
                         ws_size >= ((size_t)(1 << 20) + gi16_bytes);
    if (!use_new && !use_f32 && !use_b16) return;

    gru_init<<<dim3(256), dim3(256), 0, stream>>>(h0, h16, flags);

    if (use_new) {
        unsigned short* xb = (unsigned short*)(ws + xb_off);
        unsigned short* wb = (unsigned short*)(ws + wb_off);
        conv_b16<<<dim3(68608), dim3(256), 0, stream>>>(x, Wih, xb, wb);
        unsigned short* gi16_p = (unsigned short*)gi;
        const unsigned short* xb_c = xb;
        const unsigned short* wb_c = wb;
        const float* bih_c = bih;
        const float* Whh_c = Whh;
        const float* h0_c = h0;
        unsigned short* h16_c = h16;
        int* flags_c = flags;
        float* out_c = out;
        void* args[] = { (void*)&gi16_p, (void*)&xb_c, (void*)&wb_c, (void*)&bih_c,
                         (void*)&Whh_c, (void*)&h0_c, (void*)&h16_c,
                         (void*)&flags_c, (void*)&out_c };
        hipLaunchCooperativeKernel((const void*)&gru_fused, dim3(256), dim3(512),
                                   args, 0, stream);
    } else {
        const void* gi_c = gi;
        const float* Whh_c = Whh;
        const float* h0_c = h0;
        unsigned short* h16_c = h16;
        int* flags_c = flags;
        float* out_c = out;
        void* args[] = { (void*)&gi_c, (void*)&Whh_c, (void*)&h0_c,
                         (void*)&h16_c, (void*)&flags_c, (void*)&out_c };
        if (use_f32) {
            gi_gemm<0><<<dim3(24, 512), dim3(256), 0, stream>>>(x, Wih, bih, gi);
            hipLaunchCooperativeKernel((const void*)&gru_scan<0>, dim3(128), dim3(512),
                                       args, 0, stream);
        } else {
            gi_gemm<1><<<dim3(24, 512), dim3(256), 0, stream>>>(x, Wih, bih, gi);
            hipLaunchCooperativeKernel((const void*)&gru_scan<1>, dim3(128), dim3(512),
                                       args, 0, stream);
        }
    }
}